// Round 1
// 2088.174 us; speedup vs baseline: 1.0003x; 1.0003x over previous
//
#include <hip/hip_runtime.h>
#include <hip/hip_bf16.h>
#include <math.h>

#define B_ 16384
#define D_ 2048
#define H_ 2048
#define E_ 6
#define C_ 1024

typedef __attribute__((ext_vector_type(8))) short short8;
typedef __attribute__((ext_vector_type(4))) float f32x4;

__device__ __forceinline__ unsigned short f2bf(float f) {
    __hip_bfloat16 h = __float2bfloat16(f);
    return *reinterpret_cast<unsigned short*>(&h);
}

__device__ __forceinline__ void async_copy16(const unsigned short* g, unsigned short* l) {
    __builtin_amdgcn_global_load_lds(
        (const __attribute__((address_space(1))) unsigned int*)(g),
        (__attribute__((address_space(3))) unsigned int*)(l), 16, 0, 0);
}

// ---------------- gate: fp64 logits, top-3, softmax, routing lists ----------------
__global__ void gate_kernel(const float* __restrict__ x, const float* __restrict__ gW,
                            const float* __restrict__ gb, float* __restrict__ gw_out,
                            int* __restrict__ counts, int* __restrict__ rowlist,
                            float* __restrict__ wtslist) {
    int wave = threadIdx.x >> 6;
    int lane = threadIdx.x & 63;
    int row  = blockIdx.x * 4 + wave;
    const float* xr = x + (size_t)row * D_;
    double acc[E_] = {0, 0, 0, 0, 0, 0};
    for (int i = 0; i < D_ / 64; ++i) {
        int d = i * 64 + lane;
        double xv = (double)xr[d];
#pragma unroll
        for (int e = 0; e < E_; ++e) acc[e] += xv * (double)gW[e * D_ + d];
    }
#pragma unroll
    for (int off = 32; off > 0; off >>= 1) {
#pragma unroll
        for (int e = 0; e < E_; ++e) acc[e] += __shfl_down(acc[e], off);
    }
    if (lane == 0) {
        double lg[E_];
#pragma unroll
        for (int e = 0; e < E_; ++e) lg[e] = acc[e] + (double)gb[e];
        bool used[E_] = {false, false, false, false, false, false};
        int idx[3]; double val[3];
        for (int k = 0; k < 3; ++k) {
            int best = -1; double bv = -1e300;
            for (int e = 0; e < E_; ++e)
                if (!used[e] && lg[e] > bv) { bv = lg[e]; best = e; }
            used[best] = true; idx[k] = best; val[k] = bv;
        }
        double m = val[0];
        double w[3]; double s = 0.0;
        for (int k = 0; k < 3; ++k) { w[k] = exp(val[k] - m); s += w[k]; }
        float gwv[E_] = {0.f, 0.f, 0.f, 0.f, 0.f, 0.f};
        for (int k = 0; k < 3; ++k) gwv[idx[k]] = (float)(w[k] / s);
#pragma unroll
        for (int e = 0; e < E_; ++e) gw_out[(size_t)row * E_ + e] = gwv[e];
        for (int k = 0; k < 3; ++k) {
            int e = idx[k];
            int pos = atomicAdd(&counts[e], 1);
            rowlist[(size_t)e * B_ + pos] = row * 3 + k;   // global slot id
            wtslist[(size_t)e * B_ + pos] = (float)(w[k] / s);
        }
    }
}

// ---------------- f32 -> bf16 cast (vectorized) ----------------
__global__ void cast_f32_bf16(const float* __restrict__ in, unsigned short* __restrict__ out, int n4) {
    int i = blockIdx.x * blockDim.x + threadIdx.x;
    if (i < n4) {
        float4 v = ((const float4*)in)[i];
        ushort4 u;
        u.x = f2bf(v.x); u.y = f2bf(v.y); u.z = f2bf(v.z); u.w = f2bf(v.w);
        ((ushort4*)out)[i] = u;
    }
}

// =====================================================================
// 256x128-tile, BK=64, 8-wave (4M x 2N), TRIPLE-buffered counted-vmcnt
// pipeline (T3+T4), XOR-swizzled LDS (T2), setprio around MFMA (T5).
//
// Pipeline invariant: while computing K-tile t (resident in buf t%3),
// tile t+1 is resident in buf (t+1)%3, and tile t+2 is being staged into
// buf (t+2)%3 (which held tile t-1, fully consumed before t started).
// Each thread issues 6 global_load_lds per tile (4 A + 2 B), so the
// boundary wait vmcnt(6) == "everything except tile t+2's loads has
// landed" => tile t+1 is provably resident; never drains to 0 in the
// steady state (epilogue drains 6 -> 0, guide's T3/T4 recipe).
//
// LDS swizzle (unchanged from verified baseline, bank-conflict == 0):
// physical granule p of row r holds logical granule p ^ (r & 7);
// staging pre-swizzles the *global* source (m173), reads XOR on the way
// out. Row base is a multiple of 16 so (row&7) == (fm&7).
// =====================================================================

#define GEMM_PROLOGUE_AND_LOOP(KDIM)                                                     \
    int lane = tid & 63;                                                                 \
    int wv   = tid >> 6;                                                                 \
    int wrow = (wv >> 1) * 64;                                                           \
    int wcol = (wv & 1) * 64;                                                            \
    int fm   = lane & 15;                                                                \
    int kg   = lane >> 4;                                                                \
    int fsw  = fm & 7;                                                                   \
    f32x4 acc[4][4] = {};                                                                \
    unsigned short* A0 = As;                unsigned short* Bq0 = Bs;                    \
    unsigned short* A1 = As + 256 * 64;     unsigned short* Bq1 = Bs + 128 * 64;         \
    unsigned short* A2 = As + 2 * 256 * 64; unsigned short* Bq2 = Bs + 2 * 128 * 64;     \
    _Pragma("unroll")                                                                    \
    for (int it = 0; it < 4; ++it) async_copy16(aptr[it], A0 + (it * 512 + tid) * 8);    \
    _Pragma("unroll")                                                                    \
    for (int it = 0; it < 2; ++it) async_copy16(bptr[it], Bq0 + (it * 512 + tid) * 8);   \
    _Pragma("unroll")                                                                    \
    for (int it = 0; it < 4; ++it) async_copy16(aptr[it] + 64, A1 + (it * 512 + tid) * 8); \
    _Pragma("unroll")                                                                    \
    for (int it = 0; it < 2; ++it) async_copy16(bptr[it] + 64, Bq1 + (it * 512 + tid) * 8); \
    asm volatile("s_waitcnt vmcnt(6)" ::: "memory");                                     \
    __builtin_amdgcn_s_barrier();                                                        \
    __builtin_amdgcn_sched_barrier(0);                                                   \
    const int NT = (KDIM) / 64;                                                          \
    for (int t = 0; t < NT; ++t) {                                                       \
        const bool st  = (t + 2 < NT);                                                   \
        const int  k0s = (t + 2) * 64;                                                   \
        { /* ---- phase 0: k-slice 0 ---- */                                             \
            short8 aF[4], bF[4];                                                         \
            int go = (kg ^ fsw) * 8;                                                     \
            _Pragma("unroll")                                                            \
            for (int mi = 0; mi < 4; ++mi)                                               \
                aF[mi] = *(const short8*)(A0 + (wrow + mi * 16 + fm) * 64 + go);         \
            _Pragma("unroll")                                                            \
            for (int ni = 0; ni < 4; ++ni)                                               \
                bF[ni] = *(const short8*)(Bq0 + (wcol + ni * 16 + fm) * 64 + go);        \
            if (st) {                                                                    \
                async_copy16(aptr[0] + k0s, A2 + (0 * 512 + tid) * 8);                   \
                async_copy16(aptr[1] + k0s, A2 + (1 * 512 + tid) * 8);                   \
                async_copy16(bptr[0] + k0s, Bq2 + (0 * 512 + tid) * 8);                  \
            }                                                                            \
            __builtin_amdgcn_s_barrier();                                                \
            asm volatile("s_waitcnt lgkmcnt(0)" ::: "memory");                           \
            __builtin_amdgcn_sched_barrier(0);                                           \
            __builtin_amdgcn_s_setprio(1);                                               \
            _Pragma("unroll")                                                            \
            for (int mi = 0; mi < 4; ++mi)                                               \
                _Pragma("unroll")                                                        \
                for (int ni = 0; ni < 4; ++ni)                                           \
                    acc[mi][ni] = __builtin_amdgcn_mfma_f32_16x16x32_bf16(               \
                        aF[mi], bF[ni], acc[mi][ni], 0, 0, 0);                           \
            __builtin_amdgcn_s_setprio(0);                                               \
            __builtin_amdgcn_s_barrier();                                                \
            __builtin_amdgcn_sched_barrier(0);                                           \
        }                                                                                \
        { /* ---- phase 1: k-slice 1 ---- */                                             \
            short8 aF[4], bF[4];                                                         \
            int go = ((4 + kg) ^ fsw) * 8;                                               \
            _Pragma("unroll")                                                            \
            for (int mi = 0; mi < 4; ++mi)                                               \
                aF[mi] = *(const short8*)(A0 + (wrow + mi * 16 + fm) * 64 + go);         \
            _Pragma("unroll")                                                            \
            for (int ni = 0; ni < 4; ++ni)                                               \
                bF[ni] = *(const short8*)(Bq0 + (wcol + ni * 16 + fm) * 64 + go);        \
            if (st) {                                                                    \
                async_copy16(aptr[2] + k0s, A2 + (2 * 512 + tid) * 8);                   \
                async_copy16(aptr[3] + k0s, A2 + (3 * 512 + tid) * 8);                   \
                async_copy16(bptr[1] + k0s, Bq2 + (1 * 512 + tid) * 8);                  \
            }                                                                            \
            __builtin_amdgcn_s_barrier();                                                \
            asm volatile("s_waitcnt lgkmcnt(0)" ::: "memory");                           \
            __builtin_amdgcn_sched_barrier(0);                                           \
            __builtin_amdgcn_s_setprio(1);                                               \
            _Pragma("unroll")                                                            \
            for (int mi = 0; mi < 4; ++mi)                                               \
                _Pragma("unroll")                                                        \
                for (int ni = 0; ni < 4; ++ni)                                           \
                    acc[mi][ni] = __builtin_amdgcn_mfma_f32_16x16x32_bf16(               \
                        aF[mi], bF[ni], acc[mi][ni], 0, 0, 0);                           \
            __builtin_amdgcn_s_setprio(0);                                               \
        }                                                                                \
        /* ---- tile boundary: counted wait (tile t+1 resident; t+2 in flight) ---- */   \
        if (st) asm volatile("s_waitcnt vmcnt(6)" ::: "memory");                         \
        else    asm volatile("s_waitcnt vmcnt(0)" ::: "memory");                         \
        __builtin_amdgcn_s_barrier();                                                    \
        __builtin_amdgcn_sched_barrier(0);                                               \
        unsigned short* tA = A0; A0 = A1; A1 = A2; A2 = tA;                              \
        unsigned short* tB = Bq0; Bq0 = Bq1; Bq1 = Bq2; Bq2 = tB;                        \
    }

// ---------------- GEMM1: h[slot, n] = gelu(x[row] @ W1[e]^T + b1[e]) ----------------
__global__ __launch_bounds__(512, 2) void gemm1_kernel(
    const unsigned short* __restrict__ xb, const unsigned short* __restrict__ W1b,
    const float* __restrict__ b1, const int* __restrict__ counts,
    const int* __restrict__ rowlist, unsigned short* __restrict__ hbuf) {
    int e = blockIdx.z;
    int cnt = counts[e];
    int m0 = blockIdx.y * 256;
    if (m0 >= cnt) return;
    int n0 = blockIdx.x * 128;

    __shared__ __align__(16) unsigned short As[3 * 256 * 64];   // 96 KiB
    __shared__ __align__(16) unsigned short Bs[3 * 128 * 64];   // 48 KiB

    int tid = threadIdx.x;
    const int* rlist = rowlist + (size_t)e * B_;

    const unsigned short* aptr[4];
    const unsigned short* bptr[2];
#pragma unroll
    for (int it = 0; it < 4; ++it) {
        int seg = it * 512 + tid;
        int r = seg >> 3, c = seg & 7;
        int cs = c ^ (r & 7);                 // source-side swizzle
        int idx = m0 + r; if (idx >= cnt) idx = cnt - 1;
        aptr[it] = xb + (size_t)(rlist[idx] / 3) * D_ + cs * 8;
    }
#pragma unroll
    for (int it = 0; it < 2; ++it) {
        int seg = it * 512 + tid;
        int r = seg >> 3, c = seg & 7;
        int cs = c ^ (r & 7);
        bptr[it] = W1b + (size_t)e * H_ * D_ + (size_t)(n0 + r) * D_ + cs * 8;
    }

    GEMM_PROLOGUE_AND_LOOP(D_)

    int rlim = cnt - m0;
#pragma unroll
    for (int mi = 0; mi < 4; ++mi) {
#pragma unroll
        for (int i = 0; i < 4; ++i) {
            int r = wrow + mi * 16 + kg * 4 + i;
            if (r < rlim) {
                size_t base = (size_t)rlist[m0 + r] * H_ + n0;
#pragma unroll
                for (int ni = 0; ni < 4; ++ni) {
                    int col = wcol + ni * 16 + fm;
                    float v = acc[mi][ni][i] + b1[e * H_ + n0 + col];
                    v = 0.5f * v * (1.0f + erff(v * 0.70710678118654752f)); // exact GELU
                    hbuf[base + col] = f2bf(v);
                }
            }
        }
    }
}

// ---------------- GEMM2: sbuf[slot] = w * (h[slot] @ W2[e]^T + b2[e]) ----------------
// (or atomic-add into out when the workspace can't fit sbuf)
__global__ __launch_bounds__(512, 2) void gemm2_kernel(
    const unsigned short* __restrict__ hbuf, const unsigned short* __restrict__ W2b,
    const float* __restrict__ b2, const int* __restrict__ counts,
    const int* __restrict__ rowlist, const float* __restrict__ wtslist,
    float* __restrict__ sbuf, float* __restrict__ out) {
    int e = blockIdx.z;
    int cnt = counts[e];
    int m0 = blockIdx.y * 256;
    if (m0 >= cnt) return;
    int n0 = blockIdx.x * 128;

    __shared__ __align__(16) unsigned short As[3 * 256 * 64];   // 96 KiB
    __shared__ __align__(16) unsigned short Bs[3 * 128 * 64];   // 48 KiB

    int tid = threadIdx.x;
    const int* rlist = rowlist + (size_t)e * B_;
    const float* wlist = wtslist + (size_t)e * B_;

    const unsigned short* aptr[4];
    const unsigned short* bptr[2];
#pragma unroll
    for (int it = 0; it < 4; ++it) {
        int seg = it * 512 + tid;
        int r = seg >> 3, c = seg & 7;
        int cs = c ^ (r & 7);
        int idx = m0 + r; if (idx >= cnt) idx = cnt - 1;
        aptr[it] = hbuf + (size_t)rlist[idx] * H_ + cs * 8;
    }
#pragma unroll
    for (int it = 0; it < 2; ++it) {
        int seg = it * 512 + tid;
        int r = seg >> 3, c = seg & 7;
        int cs = c ^ (r & 7);
        bptr[it] = W2b + (size_t)e * C_ * H_ + (size_t)(n0 + r) * H_ + cs * 8;
    }

    GEMM_PROLOGUE_AND_LOOP(H_)

    int rlim = cnt - m0;
#pragma unroll
    for (int mi = 0; mi < 4; ++mi) {
#pragma unroll
        for (int i = 0; i < 4; ++i) {
            int r = wrow + mi * 16 + kg * 4 + i;
            if (r < rlim) {
                int slot = rlist[m0 + r];
                float w  = wlist[m0 + r];
                if (sbuf) {
                    // exclusive ownership: this block owns slot-row x [n0, n0+128)
                    float* srow = sbuf + (size_t)slot * C_ + n0;
#pragma unroll
                    for (int ni = 0; ni < 4; ++ni) {
                        int col = wcol + ni * 16 + fm;
                        srow[col] = (acc[mi][ni][i] + b2[e * C_ + n0 + col]) * w;
                    }
                } else {
                    float* orow = out + (size_t)(slot / 3) * C_ + n0;
#pragma unroll
                    for (int ni = 0; ni < 4; ++ni) {
                        int col = wcol + ni * 16 + fm;
                        atomicAdd(&orow[col], (acc[mi][ni][i] + b2[e * C_ + n0 + col]) * w);
                    }
                }
            }
        }
    }
}

// ---------------- combine: out[row] = sum of the row's 3 slot rows ----------------
__global__ void combine_kernel(const float* __restrict__ sbuf, float* __restrict__ out) {
    int i   = blockIdx.x * 256 + threadIdx.x;   // over B*C/4
    int row = i >> 8;                           // C/4 = 256 float4 per row
    int c4  = i & 255;
    const float4* s4 = (const float4*)sbuf;
    size_t b = (size_t)row * 3 * 256 + c4;
    float4 a = s4[b], d = s4[b + 256], g = s4[b + 512];
    float4 r;
    r.x = a.x + d.x + g.x; r.y = a.y + d.y + g.y;
    r.z = a.z + d.z + g.z; r.w = a.w + d.w + g.w;
    ((float4*)out)[i] = r;
}

extern "C" void kernel_launch(void* const* d_in, const int* in_sizes, int n_in,
                              void* d_out, int out_size, void* d_ws, size_t ws_size,
                              hipStream_t stream) {
    const float* x  = (const float*)d_in[0];
    const float* gW = (const float*)d_in[1];
    const float* gb = (const float*)d_in[2];
    const float* W1 = (const float*)d_in[3];
    const float* b1 = (const float*)d_in[4];
    const float* W2 = (const float*)d_in[5];
    const float* b2 = (const float*)d_in[6];
    float* out    = (float*)d_out;                 // [B, C]
    float* gw_out = out + (size_t)B_ * C_;         // [B, E]

    char* ws = (char*)d_ws;
    size_t off = 0;
    auto alloc = [&](size_t bytes) -> char* {
        char* p = ws + off;
        off = (off + bytes + 255) & ~(size_t)255;
        return p;
    };
    int*            counts  = (int*)alloc(E_ * 4);
    int*            rowlist = (int*)alloc((size_t)E_ * B_ * 4);
    float*          wtslist = (float*)alloc((size_t)E_ * B_ * 4);
    unsigned short* xb      = (unsigned short*)alloc((size_t)B_ * D_ * 2);
    unsigned short* W1b     = (unsigned short*)alloc((size_t)E_ * H_ * D_ * 2);
    unsigned short* W2b     = (unsigned short*)alloc((size_t)E_ * C_ * H_ * 2);
    unsigned short* hbuf    = (unsigned short*)alloc((size_t)3 * B_ * H_ * 2);
    float*          sbuf    = (float*)alloc((size_t)3 * B_ * C_ * 4);
    bool use_sbuf = (ws_size == 0) || (off <= ws_size);   // fall back to atomics if ws too small
    (void)in_sizes; (void)n_in; (void)out_size;

    hipMemsetAsync(counts, 0, E_ * 4, stream);
    if (!use_sbuf) hipMemsetAsync(out, 0, (size_t)B_ * C_ * 4, stream);

    gate_kernel<<<B_ / 4, 256, 0, stream>>>(x, gW, gb, gw_out, counts, rowlist, wtslist);
    cast_f32_bf16<<<(B_ * D_ / 4) / 256, 256, 0, stream>>>(x, xb, B_ * D_ / 4);
    cast_f32_bf16<<<(E_ * H_ * D_ / 4) / 256, 256, 0, stream>>>(W1, W1b, E_ * H_ * D_ / 4);
    cast_f32_bf16<<<(E_ * C_ * H_ / 4) / 256, 256, 0, stream>>>(W2, W2b, E_ * C_ * H_ / 4);
    gemm1_kernel<<<dim3(H_ / 128, B_ / 256, E_), 512, 0, stream>>>(xb, W1b, b1, counts, rowlist, hbuf);
    gemm2_kernel<<<dim3(C_ / 128, B_ / 256, E_), 512, 0, stream>>>(hbuf, W2b, b2, counts, rowlist, wtslist,
                                                                   use_sbuf ? sbuf : (float*)nullptr, out);
    if (use_sbuf)
        combine_kernel<<<(B_ * C_ / 4) / 256, 256, 0, stream>>>(sbuf, out);
}

// Round 3
// 2050.134 us; speedup vs baseline: 1.0189x; 1.0186x over previous
//
#include <hip/hip_runtime.h>
#include <hip/hip_bf16.h>
#include <math.h>

#define B_ 16384
#define D_ 2048
#define H_ 2048
#define E_ 6
#define C_ 1024

typedef __attribute__((ext_vector_type(8))) short short8;
typedef __attribute__((ext_vector_type(4))) float f32x4;

__device__ __forceinline__ unsigned short f2bf(float f) {
    __hip_bfloat16 h = __float2bfloat16(f);
    return *reinterpret_cast<unsigned short*>(&h);
}

__device__ __forceinline__ void async_copy16(const unsigned short* g, unsigned short* l) {
    __builtin_amdgcn_global_load_lds(
        (const __attribute__((address_space(1))) unsigned int*)(g),
        (__attribute__((address_space(3))) unsigned int*)(l), 16, 0, 0);
}

// ---------------- gate: fp64 logits, top-3, softmax, routing lists + fused x->bf16 cast ----------------
__global__ void gate_kernel(const float* __restrict__ x, const float* __restrict__ gW,
                            const float* __restrict__ gb, float* __restrict__ gw_out,
                            int* __restrict__ counts, int* __restrict__ rowlist,
                            float* __restrict__ wtslist, unsigned short* __restrict__ xb) {
    int wave = threadIdx.x >> 6;
    int lane = threadIdx.x & 63;
    int row  = blockIdx.x * 4 + wave;
    const float* xr = x + (size_t)row * D_;
    unsigned short* xbr = xb + (size_t)row * D_;
    double acc[E_] = {0, 0, 0, 0, 0, 0};
    for (int i = 0; i < D_ / 64; ++i) {
        int d = i * 64 + lane;
        float xf = xr[d];
        xbr[d] = f2bf(xf);                       // fused cast (saves a separate 128MB-read pass)
        double xv = (double)xf;
#pragma unroll
        for (int e = 0; e < E_; ++e) acc[e] += xv * (double)gW[e * D_ + d];
    }
#pragma unroll
    for (int off = 32; off > 0; off >>= 1) {
#pragma unroll
        for (int e = 0; e < E_; ++e) acc[e] += __shfl_down(acc[e], off);
    }
    if (lane == 0) {
        double lg[E_];
#pragma unroll
        for (int e = 0; e < E_; ++e) lg[e] = acc[e] + (double)gb[e];
        bool used[E_] = {false, false, false, false, false, false};
        int idx[3]; double val[3];
        for (int k = 0; k < 3; ++k) {
            int best = -1; double bv = -1e300;
            for (int e = 0; e < E_; ++e)
                if (!used[e] && lg[e] > bv) { bv = lg[e]; best = e; }
            used[best] = true; idx[k] = best; val[k] = bv;
        }
        double m = val[0];
        double w[3]; double s = 0.0;
        for (int k = 0; k < 3; ++k) { w[k] = exp(val[k] - m); s += w[k]; }
        float gwv[E_] = {0.f, 0.f, 0.f, 0.f, 0.f, 0.f};
        for (int k = 0; k < 3; ++k) gwv[idx[k]] = (float)(w[k] / s);
#pragma unroll
        for (int e = 0; e < E_; ++e) gw_out[(size_t)row * E_ + e] = gwv[e];
        for (int k = 0; k < 3; ++k) {
            int e = idx[k];
            int pos = atomicAdd(&counts[e], 1);
            rowlist[(size_t)e * B_ + pos] = row * 3 + k;   // global slot id
            wtslist[(size_t)e * B_ + pos] = (float)(w[k] / s);
        }
    }
}

// ---------------- f32 -> bf16 cast (vectorized) ----------------
__global__ void cast_f32_bf16(const float* __restrict__ in, unsigned short* __restrict__ out, int n4) {
    int i = blockIdx.x * blockDim.x + threadIdx.x;
    if (i < n4) {
        float4 v = ((const float4*)in)[i];
        ushort4 u;
        u.x = f2bf(v.x); u.y = f2bf(v.y); u.z = f2bf(v.z); u.w = f2bf(v.w);
        ((ushort4*)out)[i] = u;
    }
}

// =====================================================================
// 256x256 tile, BK=32, 8 waves (2M x 4N, per-wave 128x64 output),
// 4 LDS buffers (128 KiB), ledger-clean 3-tile-deep prefetch:
//   while computing tile t (buf t%4), stage tile t+3 into buf (t+3)%4
//   (== buf (t-1)%4, fully consumed before t started). One boundary per
//   tile: vmcnt(8) [tiles t+2,t+3 in flight] + s_barrier + sched_barrier.
//   Epilogue drains 8 -> 4 -> 0.  Never drains vmcnt to 0 mid-loop (T4).
//
// Arithmetic intensity: 256x256x32x2 FLOP per 32 KiB staged = 128 FLOP/B
// (vs 85 at 256x128), matching per-CU L2 supply (~56 B/cyc).
//
// LDS layout (bank-conflict-free): logical tile [256][32] bf16 stored as
// [128][64]: LDS row r holds tile rows {2r, 2r+1}; granule (16B) index
// p_phys = p_logical ^ (r & 7)  -- same proven XOR geometry as baseline
// (each 128B LDS row's 8 lanes read 8 distinct granules => 0 conflicts).
// Staging pre-applies the inverse permutation on the *global* source
// address (m173/rule #21: linear LDS dest, swizzled source).
// =====================================================================

#define GEMM_CORE(KDIM)                                                          \
    int lane = tid & 63;                                                         \
    int wv   = tid >> 6;                                                         \
    int wr   = wv >> 2;   /* 0..1: M half  */                                    \
    int wc   = wv & 3;    /* 0..3: N quarter */                                  \
    int fm   = lane & 15;                                                        \
    int kg   = lane >> 4;                                                        \
    int laneoff = ((fm >> 1) << 6) + ((((fm & 1) << 2) + kg) ^ ((fm >> 1) & 7)) * 8; \
    int aBase = wr * 4096 + laneoff;                                             \
    int bBase = wc * 2048 + laneoff;                                             \
    f32x4 acc[8][4] = {};                                                        \
    const int NT = (KDIM) / 32;                                                  \
    _Pragma("unroll")                                                            \
    for (int pt = 0; pt < 3; ++pt) {                                             \
        unsigned short* Ab = As + pt * 8192;                                     \
        unsigned short* Bb = Bs + pt * 8192;                                     \
        int k0 = pt * 32;                                                        \
        async_copy16(aptr[0] + k0, Ab + (0 * 512 + tid) * 8);                    \
        async_copy16(aptr[1] + k0, Ab + (1 * 512 + tid) * 8);                    \
        async_copy16(bptr[0] + k0, Bb + (0 * 512 + tid) * 8);                    \
        async_copy16(bptr[1] + k0, Bb + (1 * 512 + tid) * 8);                    \
    }                                                                            \
    asm volatile("s_waitcnt vmcnt(8)" ::: "memory");                             \
    __builtin_amdgcn_s_barrier();                                                \
    __builtin_amdgcn_sched_barrier(0);                                           \
    for (int t = 0; t < NT; ++t) {                                               \
        unsigned short* Ab = As + (t & 3) * 8192;                                \
        unsigned short* Bb = Bs + (t & 3) * 8192;                                \
        if (t + 3 < NT) {                                                        \
            unsigned short* An = As + ((t + 3) & 3) * 8192;                      \
            unsigned short* Bn = Bs + ((t + 3) & 3) * 8192;                      \
            int k0 = (t + 3) * 32;                                               \
            async_copy16(aptr[0] + k0, An + (0 * 512 + tid) * 8);                \
            async_copy16(aptr[1] + k0, An + (1 * 512 + tid) * 8);                \
            async_copy16(bptr[0] + k0, Bn + (0 * 512 + tid) * 8);                \
            async_copy16(bptr[1] + k0, Bn + (1 * 512 + tid) * 8);                \
        }                                                                        \
        short8 bF[4];                                                            \
        _Pragma("unroll")                                                        \
        for (int n = 0; n < 4; ++n)                                              \
            bF[n] = *(const short8*)(Bb + bBase + n * 512);                      \
        _Pragma("unroll")                                                        \
        for (int m = 0; m < 8; ++m) {                                            \
            short8 aF = *(const short8*)(Ab + aBase + m * 512);                  \
            _Pragma("unroll")                                                    \
            for (int n = 0; n < 4; ++n)                                          \
                acc[m][n] = __builtin_amdgcn_mfma_f32_16x16x32_bf16(             \
                    aF, bF[n], acc[m][n], 0, 0, 0);                              \
        }                                                                        \
        if (t + 3 < NT)      asm volatile("s_waitcnt vmcnt(8)" ::: "memory");    \
        else if (t + 2 < NT) asm volatile("s_waitcnt vmcnt(4)" ::: "memory");    \
        else                 asm volatile("s_waitcnt vmcnt(0)" ::: "memory");    \
        __builtin_amdgcn_s_barrier();                                            \
        __builtin_amdgcn_sched_barrier(0);                                       \
    }

// slot -> (tile row R, k-granule g) decode for staging (inverse of the read swizzle)
#define SLOT_DECODE(s, R, g)                                                     \
    int rr_##R = (s) >> 3;                                                       \
    int pp_##R = ((s) & 7) ^ (rr_##R & 7);                                       \
    int R = 2 * rr_##R + (pp_##R >> 2);                                          \
    int g = pp_##R & 3;

// ---------------- GEMM1: h[slot, n] = gelu(x[row] @ W1[e]^T + b1[e]) ----------------
__global__ __launch_bounds__(512, 2) void gemm1_kernel(
    const unsigned short* __restrict__ xb, const unsigned short* __restrict__ W1b,
    const float* __restrict__ b1, const int* __restrict__ counts,
    const int* __restrict__ rowlist, unsigned short* __restrict__ hbuf) {
    int e = blockIdx.z;
    int cnt = counts[e];
    // XCD-panel rasterization: all 8 n-blocks of an m-panel land on one XCD
    int flat = blockIdx.x;                      // grid.x = 8 * 64 = 512
    int p  = (flat & 7) + ((flat >> 6) << 3);   // m-panel 0..63
    int nb = (flat >> 3) & 7;                   // n-block 0..7
    int m0 = p * 256;
    if (m0 >= cnt) return;
    int n0 = nb * 256;

    __shared__ __align__(16) unsigned short As[4 * 8192];   // 64 KiB
    __shared__ __align__(16) unsigned short Bs[4 * 8192];   // 64 KiB
    int tid = threadIdx.x;
    const int* rlist = rowlist + (size_t)e * B_;

    const unsigned short* aptr[2];
    const unsigned short* bptr[2];
#pragma unroll
    for (int it = 0; it < 2; ++it) {
        int s = it * 512 + tid;
        SLOT_DECODE(s, Ra, ga)
        int idx = m0 + Ra; if (idx >= cnt) idx = cnt - 1;
        aptr[it] = xb + (size_t)(rlist[idx] / 3) * D_ + ga * 8;
        bptr[it] = W1b + (size_t)e * H_ * D_ + (size_t)(n0 + Ra) * D_ + ga * 8;
    }

    GEMM_CORE(D_)

    int rlim = cnt - m0;
#pragma unroll
    for (int m = 0; m < 8; ++m) {
#pragma unroll
        for (int i = 0; i < 4; ++i) {
            int r = wr * 128 + m * 16 + kg * 4 + i;
            if (r < rlim) {
                size_t base = (size_t)rlist[m0 + r] * H_ + n0;
#pragma unroll
                for (int n = 0; n < 4; ++n) {
                    int col = wc * 64 + n * 16 + fm;
                    float v = acc[m][n][i] + b1[e * H_ + n0 + col];
                    v = 0.5f * v * (1.0f + erff(v * 0.70710678118654752f)); // exact GELU
                    hbuf[base + col] = f2bf(v);
                }
            }
        }
    }
}

// ---------------- GEMM2: sbuf[slot] = w * (h[slot] @ W2[e]^T + b2[e]) ----------------
__global__ __launch_bounds__(512, 2) void gemm2_kernel(
    const unsigned short* __restrict__ hbuf, const unsigned short* __restrict__ W2b,
    const float* __restrict__ b2, const int* __restrict__ counts,
    const int* __restrict__ rowlist, const float* __restrict__ wtslist,
    float* __restrict__ sbuf, float* __restrict__ out) {
    int e = blockIdx.z;
    int cnt = counts[e];
    int flat = blockIdx.x;                      // grid.x = 4 * 64 = 256
    int p  = (flat & 7) + ((flat >> 5) << 3);   // m-panel 0..63
    int nb = (flat >> 3) & 3;                   // n-block 0..3
    int m0 = p * 256;
    if (m0 >= cnt) return;
    int n0 = nb * 256;

    __shared__ __align__(16) unsigned short As[4 * 8192];
    __shared__ __align__(16) unsigned short Bs[4 * 8192];
    int tid = threadIdx.x;
    const int* rlist = rowlist + (size_t)e * B_;
    const float* wlist = wtslist + (size_t)e * B_;

    const unsigned short* aptr[2];
    const unsigned short* bptr[2];
#pragma unroll
    for (int it = 0; it < 2; ++it) {
        int s = it * 512 + tid;
        SLOT_DECODE(s, Ra, ga)
        int idx = m0 + Ra; if (idx >= cnt) idx = cnt - 1;
        aptr[it] = hbuf + (size_t)rlist[idx] * H_ + ga * 8;
        bptr[it] = W2b + (size_t)e * C_ * H_ + (size_t)(n0 + Ra) * H_ + ga * 8;
    }

    GEMM_CORE(H_)

    int rlim = cnt - m0;
#pragma unroll
    for (int m = 0; m < 8; ++m) {
#pragma unroll
        for (int i = 0; i < 4; ++i) {
            int r = wr * 128 + m * 16 + kg * 4 + i;
            if (r < rlim) {
                int slot = rlist[m0 + r];
                float w  = wlist[m0 + r];
                if (sbuf) {
                    float* srow = sbuf + (size_t)slot * C_ + n0;   // exclusive ownership
#pragma unroll
                    for (int n = 0; n < 4; ++n) {
                        int col = wc * 64 + n * 16 + fm;
                        srow[col] = (acc[m][n][i] + b2[e * C_ + n0 + col]) * w;
                    }
                } else {
                    float* orow = out + (size_t)(slot / 3) * C_ + n0;
#pragma unroll
                    for (int n = 0; n < 4; ++n) {
                        int col = wc * 64 + n * 16 + fm;
                        atomicAdd(&orow[col], (acc[m][n][i] + b2[e * C_ + n0 + col]) * w);
                    }
                }
            }
        }
    }
}

// ---------------- combine: out[row] = sum of the row's 3 slot rows ----------------
__global__ void combine_kernel(const float* __restrict__ sbuf, float* __restrict__ out) {
    int i   = blockIdx.x * 256 + threadIdx.x;   // over B*C/4
    int row = i >> 8;                           // C/4 = 256 float4 per row
    int c4  = i & 255;
    const float4* s4 = (const float4*)sbuf;
    size_t b = (size_t)row * 3 * 256 + c4;
    float4 a = s4[b], d = s4[b + 256], g = s4[b + 512];
    float4 r;
    r.x = a.x + d.x + g.x; r.y = a.y + d.y + g.y;
    r.z = a.z + d.z + g.z; r.w = a.w + d.w + g.w;
    ((float4*)out)[i] = r;
}

extern "C" void kernel_launch(void* const* d_in, const int* in_sizes, int n_in,
                              void* d_out, int out_size, void* d_ws, size_t ws_size,
                              hipStream_t stream) {
    const float* x  = (const float*)d_in[0];
    const float* gW = (const float*)d_in[1];
    const float* gb = (const float*)d_in[2];
    const float* W1 = (const float*)d_in[3];
    const float* b1 = (const float*)d_in[4];
    const float* W2 = (const float*)d_in[5];
    const float* b2 = (const float*)d_in[6];
    float* out    = (float*)d_out;                 // [B, C]
    float* gw_out = out + (size_t)B_ * C_;         // [B, E]

    char* ws = (char*)d_ws;
    size_t off = 0;
    auto alloc = [&](size_t bytes) -> char* {
        char* p = ws + off;
        off = (off + bytes + 255) & ~(size_t)255;
        return p;
    };
    int*            counts  = (int*)alloc(E_ * 4);
    int*            rowlist = (int*)alloc((size_t)E_ * B_ * 4);
    float*          wtslist = (float*)alloc((size_t)E_ * B_ * 4);
    unsigned short* W2b     = (unsigned short*)alloc((size_t)E_ * C_ * H_ * 2);
    unsigned short* hbuf    = (unsigned short*)alloc((size_t)3 * B_ * H_ * 2);
    // union region: {xb (64MB) + W1b (48MB)} live until gemm1; sbuf (192MB) live
    // only during gemm2+combine => alias sbuf over xb/W1b.
    size_t region_off = off;
    unsigned short* xb      = (unsigned short*)alloc((size_t)B_ * D_ * 2);
    unsigned short* W1b     = (unsigned short*)alloc((size_t)E_ * H_ * D_ * 2);
    float*          sbuf    = (float*)(ws + region_off);
    size_t sbuf_end = region_off + (size_t)3 * B_ * C_ * 4;
    bool use_sbuf = (ws_size == 0) || (sbuf_end <= ws_size);
    (void)in_sizes; (void)n_in; (void)out_size;

    hipMemsetAsync(counts, 0, E_ * 4, stream);
    if (!use_sbuf) hipMemsetAsync(out, 0, (size_t)B_ * C_ * 4, stream);

    gate_kernel<<<B_ / 4, 256, 0, stream>>>(x, gW, gb, gw_out, counts, rowlist, wtslist, xb);
    cast_f32_bf16<<<(E_ * H_ * D_ / 4) / 256, 256, 0, stream>>>(W1, W1b, E_ * H_ * D_ / 4);
    cast_f32_bf16<<<(E_ * C_ * H_ / 4) / 256, 256, 0, stream>>>(W2, W2b, E_ * C_ * H_ / 4);
    gemm1_kernel<<<dim3(8 * (B_ / 256), 1, E_), 512, 0, stream>>>(xb, W1b, b1, counts, rowlist, hbuf);
    gemm2_kernel<<<dim3(4 * (B_ / 256), 1, E_), 512, 0, stream>>>(hbuf, W2b, b2, counts, rowlist, wtslist,
                                                                  use_sbuf ? sbuf : (float*)nullptr, out);
    if (use_sbuf)
        combine_kernel<<<(B_ * C_ / 4) / 256, 256, 0, stream>>>(sbuf, out);
}

// Round 6
// 1872.601 us; speedup vs baseline: 1.1155x; 1.0948x over previous
//
#include <hip/hip_runtime.h>
#include <hip/hip_bf16.h>
#include <math.h>

#define B_ 16384
#define D_ 2048
#define H_ 2048
#define E_ 6
#define C_ 1024

#define HALF_ (128 * 64)   // elements per half-tile (128 rows x 64 k, bf16)

typedef __attribute__((ext_vector_type(8))) short short8;
typedef __attribute__((ext_vector_type(4))) float f32x4;

__device__ __forceinline__ unsigned short f2bf(float f) {
    __hip_bfloat16 h = __float2bfloat16(f);
    return *reinterpret_cast<unsigned short*>(&h);
}

__device__ __forceinline__ void async_copy16(const unsigned short* g, unsigned short* l) {
    __builtin_amdgcn_global_load_lds(
        (const __attribute__((address_space(1))) unsigned int*)(g),
        (__attribute__((address_space(3))) unsigned int*)(l), 16, 0, 0);
}

// ---------------- gate: fp64 logits, top-3, softmax, routing lists + fused x->bf16 cast ----------------
__global__ void gate_kernel(const float* __restrict__ x, const float* __restrict__ gW,
                            const float* __restrict__ gb, float* __restrict__ gw_out,
                            int* __restrict__ counts, int* __restrict__ rowlist,
                            float* __restrict__ wtslist, unsigned short* __restrict__ xb) {
    int wave = threadIdx.x >> 6;
    int lane = threadIdx.x & 63;
    int row  = blockIdx.x * 4 + wave;
    const float* xr = x + (size_t)row * D_;
    unsigned short* xbr = xb + (size_t)row * D_;
    double acc[E_] = {0, 0, 0, 0, 0, 0};
    for (int i = 0; i < D_ / 64; ++i) {
        int d = i * 64 + lane;
        float xf = xr[d];
        xbr[d] = f2bf(xf);
        double xv = (double)xf;
#pragma unroll
        for (int e = 0; e < E_; ++e) acc[e] += xv * (double)gW[e * D_ + d];
    }
#pragma unroll
    for (int off = 32; off > 0; off >>= 1) {
#pragma unroll
        for (int e = 0; e < E_; ++e) acc[e] += __shfl_down(acc[e], off);
    }
    if (lane == 0) {
        double lg[E_];
#pragma unroll
        for (int e = 0; e < E_; ++e) lg[e] = acc[e] + (double)gb[e];
        bool used[E_] = {false, false, false, false, false, false};
        int idx[3]; double val[3];
        for (int k = 0; k < 3; ++k) {
            int best = -1; double bv = -1e300;
            for (int e = 0; e < E_; ++e)
                if (!used[e] && lg[e] > bv) { bv = lg[e]; best = e; }
            used[best] = true; idx[k] = best; val[k] = bv;
        }
        double m = val[0];
        double w[3]; double s = 0.0;
        for (int k = 0; k < 3; ++k) { w[k] = exp(val[k] - m); s += w[k]; }
        float gwv[E_] = {0.f, 0.f, 0.f, 0.f, 0.f, 0.f};
        for (int k = 0; k < 3; ++k) gwv[idx[k]] = (float)(w[k] / s);
#pragma unroll
        for (int e = 0; e < E_; ++e) gw_out[(size_t)row * E_ + e] = gwv[e];
        for (int k = 0; k < 3; ++k) {
            int e = idx[k];
            int pos = atomicAdd(&counts[e], 1);
            rowlist[(size_t)e * B_ + pos] = row * 3 + k;   // global slot id
            wtslist[(size_t)e * B_ + pos] = (float)(w[k] / s);
        }
    }
}

// ---------------- f32 -> bf16 cast (vectorized) ----------------
__global__ void cast_f32_bf16(const float* __restrict__ in, unsigned short* __restrict__ out, int n4) {
    int i = blockIdx.x * blockDim.x + threadIdx.x;
    if (i < n4) {
        float4 v = ((const float4*)in)[i];
        ushort4 u;
        u.x = f2bf(v.x); u.y = f2bf(v.y); u.z = f2bf(v.z); u.w = f2bf(v.w);
        ((ushort4*)out)[i] = u;
    }
}

// =====================================================================
// m201-style 8-phase schedule (T2+T3+T4+T5), 256x256 tile, BK=64,
// 8 waves (2M x 4N; per-wave 128x64), 2 K-tile LDS buffers = 128 KiB.
//
// Per K-tile: 4 phases, each {frag ds_reads + half-tile stage issue ->
// barrier -> lgkmcnt(0)+sched_barrier -> setprio(1) -> 16 MFMA ->
// setprio(0) -> barrier}.  Stages write the CURRENT buffer's freed
// slots for K-tile t+2: B-halves at P3 (B last read at P2), A-halves
// at P4 (A last read at P3).  Boundary: vmcnt(8) = exactly this tile's
// 8 stage-loads outstanding => tile t+1 fenced; barrier makes it
// visible to all waves.  Prologue stages tiles 0,1 (16 loads) then
// vmcnt(8).  Last two tiles use vmcnt(0) (drain).  Never drains
// mid-loop (T4).
//
// LDS: per half [128][64] bf16, granule(16B)-XOR swizzle p^=(row&7)
// (verified 0-conflict in rounds 0-3); staging pre-applies the inverse
// permutation on the GLOBAL source address (linear LDS dest, rule #21).
// =====================================================================

#define PHASE_IN()                                                               \
    __builtin_amdgcn_sched_barrier(0);                                           \
    __builtin_amdgcn_s_barrier();                                                \
    asm volatile("s_waitcnt lgkmcnt(0)" ::: "memory");                           \
    __builtin_amdgcn_sched_barrier(0);                                           \
    __builtin_amdgcn_s_setprio(1);

#define PHASE_OUT()                                                              \
    __builtin_amdgcn_s_setprio(0);                                               \
    __builtin_amdgcn_sched_barrier(0);                                           \
    __builtin_amdgcn_s_barrier();

#define STAGE_A(dstbuf, koff)                                                    \
    _Pragma("unroll")                                                            \
    for (int h_ = 0; h_ < 2; ++h_)                                               \
        _Pragma("unroll")                                                        \
        for (int j_ = 0; j_ < 2; ++j_)                                           \
            async_copy16(asrc[h_][j_] + (koff),                                  \
                         (dstbuf) + h_ * HALF_ + (j_ * 512 + tid) * 8);

#define STAGE_B(dstbuf, koff)                                                    \
    _Pragma("unroll")                                                            \
    for (int h_ = 0; h_ < 2; ++h_)                                               \
        _Pragma("unroll")                                                        \
        for (int j_ = 0; j_ < 2; ++j_)                                           \
            async_copy16(bsrc[h_][j_] + (koff),                                  \
                         (dstbuf) + h_ * HALF_ + (j_ * 512 + tid) * 8);

#define MFMA_BF16 __builtin_amdgcn_mfma_f32_16x16x32_bf16

#define GEMM_CORE(KDIM)                                                          \
    int lane = tid & 63;                                                         \
    int wv = tid >> 6;                                                           \
    int wr = wv >> 2;   /* 0..1: M half   */                                     \
    int wc = wv & 3;    /* 0..3: N strip  */                                     \
    int fm = lane & 15;                                                          \
    int kg = lane >> 4;                                                          \
    unsigned g0 = (unsigned)((kg ^ (fm & 7)) * 8);                               \
    unsigned g1 = (unsigned)(((4 + kg) ^ (fm & 7)) * 8);                         \
    unsigned aRB = (unsigned)(wr * HALF_ + fm * 64);                             \
    unsigned bRB = (unsigned)((wc >> 1) * HALF_ + ((wc & 1) * 64 + fm) * 64);    \
    f32x4 acc[8][4] = {};                                                        \
    const int NT = (KDIM) / 64;                                                  \
    STAGE_A(As, 0) STAGE_B(Bs, 0)                                                \
    STAGE_A(As + 2 * HALF_, 64) STAGE_B(Bs + 2 * HALF_, 64)                      \
    asm volatile("s_waitcnt vmcnt(8)" ::: "memory");                             \
    __builtin_amdgcn_s_barrier();                                                \
    __builtin_amdgcn_sched_barrier(0);                                           \
    for (int t = 0; t < NT; ++t) {                                               \
        unsigned short* Ab = As + (t & 1) * (2 * HALF_);                         \
        unsigned short* Bb = Bs + (t & 1) * (2 * HALF_);                         \
        const bool st = (t + 2 < NT);                                            \
        const int koff = (t + 2) * 64;                                           \
        const unsigned short* Ar0 = Ab + aRB + g0;                               \
        const unsigned short* Ar1 = Ab + aRB + g1;                               \
        const unsigned short* Br0 = Bb + bRB + g0;                               \
        const unsigned short* Br1 = Bb + bRB + g1;                               \
        short8 aF[4][2], bQ[2][2], bR[2][2];                                     \
        /* -- P1: read A(m0-3) + B(n0-1); MFMA (m0-3 x n0-1) -- */               \
        _Pragma("unroll")                                                        \
        for (int m = 0; m < 4; ++m) {                                            \
            aF[m][0] = *(const short8*)(Ar0 + m * 1024);                         \
            aF[m][1] = *(const short8*)(Ar1 + m * 1024);                         \
        }                                                                        \
        _Pragma("unroll")                                                        \
        for (int n = 0; n < 2; ++n) {                                            \
            bQ[n][0] = *(const short8*)(Br0 + n * 1024);                         \
            bQ[n][1] = *(const short8*)(Br1 + n * 1024);                         \
        }                                                                        \
        PHASE_IN()                                                               \
        _Pragma("unroll")                                                        \
        for (int m = 0; m < 4; ++m)                                              \
            _Pragma("unroll")                                                    \
            for (int n = 0; n < 2; ++n) {                                        \
                acc[m][n] = MFMA_BF16(aF[m][0], bQ[n][0], acc[m][n], 0, 0, 0);   \
                acc[m][n] = MFMA_BF16(aF[m][1], bQ[n][1], acc[m][n], 0, 0, 0);   \
            }                                                                    \
        PHASE_OUT()                                                              \
        /* -- P2: read B(n2-3); MFMA (m0-3 x n2-3) -- */                         \
        _Pragma("unroll")                                                        \
        for (int n = 0; n < 2; ++n) {                                            \
            bR[n][0] = *(const short8*)(Br0 + (2 + n) * 1024);                   \
            bR[n][1] = *(const short8*)(Br1 + (2 + n) * 1024);                   \
        }                                                                        \
        PHASE_IN()                                                               \
        _Pragma("unroll")                                                        \
        for (int m = 0; m < 4; ++m)                                              \
            _Pragma("unroll")                                                    \
            for (int n = 0; n < 2; ++n) {                                        \
                acc[m][2 + n] = MFMA_BF16(aF[m][0], bR[n][0], acc[m][2 + n], 0, 0, 0); \
                acc[m][2 + n] = MFMA_BF16(aF[m][1], bR[n][1], acc[m][2 + n], 0, 0, 0); \
            }                                                                    \
        PHASE_OUT()                                                               \
        /* -- P3: read A(m4-7); stage B(t+2); MFMA (m4-7 x n0-1) -- */           \
        _Pragma("unroll")                                                        \
        for (int m = 0; m < 4; ++m) {                                            \
            aF[m][0] = *(const short8*)(Ar0 + (4 + m) * 1024);                   \
            aF[m][1] = *(const short8*)(Ar1 + (4 + m) * 1024);                   \
        }                                                                        \
        if (st) { STAGE_B(Bb, koff) }                                            \
        PHASE_IN()                                                               \
        _Pragma("unroll")                                                        \
        for (int m = 0; m < 4; ++m)                                              \
            _Pragma("unroll")                                                    \
            for (int n = 0; n < 2; ++n) {                                        \
                acc[4 + m][n] = MFMA_BF16(aF[m][0], bQ[n][0], acc[4 + m][n], 0, 0, 0); \
                acc[4 + m][n] = MFMA_BF16(aF[m][1], bQ[n][1], acc[4 + m][n], 0, 0, 0); \
            }                                                                    \
        PHASE_OUT()                                                              \
        /* -- P4: stage A(t+2); MFMA (m4-7 x n2-3); boundary vmcnt -- */         \
        if (st) { STAGE_A(Ab, koff) }                                            \
        PHASE_IN()                                                               \
        _Pragma("unroll")                                                        \
        for (int m = 0; m < 4; ++m)                                              \
            _Pragma("unroll")                                                    \
            for (int n = 0; n < 2; ++n) {                                        \
                acc[4 + m][2 + n] = MFMA_BF16(aF[m][0], bR[n][0], acc[4 + m][2 + n], 0, 0, 0); \
                acc[4 + m][2 + n] = MFMA_BF16(aF[m][1], bR[n][1], acc[4 + m][2 + n], 0, 0, 0); \
            }                                                                    \
        __builtin_amdgcn_s_setprio(0);                                           \
        __builtin_amdgcn_sched_barrier(0);                                       \
        if (st) asm volatile("s_waitcnt vmcnt(8)" ::: "memory");                 \
        else    asm volatile("s_waitcnt vmcnt(0)" ::: "memory");                 \
        __builtin_amdgcn_s_barrier();                                            \
        __builtin_amdgcn_sched_barrier(0);                                       \
    }

// ---------------- GEMM1: h[slot, n] = gelu(x[row] @ W1[e]^T + b1[e]) ----------------
__global__ __launch_bounds__(512, 2) void gemm1_kernel(
    const unsigned short* __restrict__ xb, const unsigned short* __restrict__ W1b,
    const float* __restrict__ b1, const int* __restrict__ counts,
    const int* __restrict__ rowlist, unsigned short* __restrict__ hbuf) {
    int e = blockIdx.z;
    int cnt = counts[e];
    // XCD-panel rasterization: the 8 n-blocks of an m-panel land on one XCD
    int flat = blockIdx.x;                      // grid.x = 8 * 64 = 512
    int p  = (flat & 7) + ((flat >> 6) << 3);   // m-panel 0..63
    int nb = (flat >> 3) & 7;                   // n-block 0..7
    int m0 = p * 256;
    if (m0 >= cnt) return;
    int n0 = nb * 256;

    __shared__ __align__(16) unsigned short As[4 * HALF_];   // 64 KiB
    __shared__ __align__(16) unsigned short Bs[4 * HALF_];   // 64 KiB
    int tid = threadIdx.x;
    const int* rlist = rowlist + (size_t)e * B_;

    // staging source pointers: thread owns granule (rb, gth) of each half
    int rb = tid >> 3;
    int gth = ((tid & 7) ^ (rb & 7)) * 8;
    const unsigned short* asrc[2][2];
    const unsigned short* bsrc[2][2];
#pragma unroll
    for (int h = 0; h < 2; ++h)
#pragma unroll
        for (int j = 0; j < 2; ++j) {
            int r = h * 128 + j * 64 + rb;
            int idx = m0 + r; if (idx >= cnt) idx = cnt - 1;
            asrc[h][j] = xb + (size_t)(rlist[idx] / 3) * D_ + gth;
            bsrc[h][j] = W1b + (size_t)e * H_ * D_ + (size_t)(n0 + r) * D_ + gth;
        }

    GEMM_CORE(D_)

    int rlim = cnt - m0;
#pragma unroll
    for (int m = 0; m < 8; ++m) {
#pragma unroll
        for (int i = 0; i < 4; ++i) {
            int r = wr * 128 + m * 16 + kg * 4 + i;
            if (r < rlim) {
                size_t base = (size_t)rlist[m0 + r] * H_ + n0;
#pragma unroll
                for (int n = 0; n < 4; ++n) {
                    int col = wc * 64 + n * 16 + fm;
                    float v = acc[m][n][i] + b1[e * H_ + n0 + col];
                    v = 0.5f * v * (1.0f + erff(v * 0.70710678118654752f)); // exact GELU
                    hbuf[base + col] = f2bf(v);
                }
            }
        }
    }
}

// ---------------- GEMM2: sbuf[slot] = w * (h[slot] @ W2[e]^T + b2[e]) ----------------
__global__ __launch_bounds__(512, 2) void gemm2_kernel(
    const unsigned short* __restrict__ hbuf, const unsigned short* __restrict__ W2b,
    const float* __restrict__ b2, const int* __restrict__ counts,
    const int* __restrict__ rowlist, const float* __restrict__ wtslist,
    float* __restrict__ sbuf, float* __restrict__ out) {
    int e = blockIdx.z;
    int cnt = counts[e];
    int flat = blockIdx.x;                      // grid.x = 4 * 64 = 256
    int p  = (flat & 7) + ((flat >> 5) << 3);   // m-panel 0..63
    int nb = (flat >> 3) & 3;                   // n-block 0..3
    int m0 = p * 256;
    if (m0 >= cnt) return;
    int n0 = nb * 256;

    __shared__ __align__(16) unsigned short As[4 * HALF_];
    __shared__ __align__(16) unsigned short Bs[4 * HALF_];
    int tid = threadIdx.x;
    const int* rlist = rowlist + (size_t)e * B_;
    const float* wlist = wtslist + (size_t)e * B_;

    int rb = tid >> 3;
    int gth = ((tid & 7) ^ (rb & 7)) * 8;
    const unsigned short* asrc[2][2];
    const unsigned short* bsrc[2][2];
#pragma unroll
    for (int h = 0; h < 2; ++h)
#pragma unroll
        for (int j = 0; j < 2; ++j) {
            int r = h * 128 + j * 64 + rb;
            int idx = m0 + r; if (idx >= cnt) idx = cnt - 1;
            asrc[h][j] = hbuf + (size_t)rlist[idx] * H_ + gth;
            bsrc[h][j] = W2b + (size_t)e * C_ * H_ + (size_t)(n0 + r) * H_ + gth;
        }

    GEMM_CORE(H_)

    int rlim = cnt - m0;
#pragma unroll
    for (int m = 0; m < 8; ++m) {
#pragma unroll
        for (int i = 0; i < 4; ++i) {
            int r = wr * 128 + m * 16 + kg * 4 + i;
            if (r < rlim) {
                int slot = rlist[m0 + r];
                float w  = wlist[m0 + r];
                if (sbuf) {
                    float* srow = sbuf + (size_t)slot * C_ + n0;   // exclusive ownership
#pragma unroll
                    for (int n = 0; n < 4; ++n) {
                        int col = wc * 64 + n * 16 + fm;
                        srow[col] = (acc[m][n][i] + b2[e * C_ + n0 + col]) * w;
                    }
                } else {
                    float* orow = out + (size_t)(slot / 3) * C_ + n0;
#pragma unroll
                    for (int n = 0; n < 4; ++n) {
                        int col = wc * 64 + n * 16 + fm;
                        atomicAdd(&orow[col], (acc[m][n][i] + b2[e * C_ + n0 + col]) * w);
                    }
                }
            }
        }
    }
}

// ---------------- combine: out[row] = sum of the row's 3 slot rows ----------------
__global__ void combine_kernel(const float* __restrict__ sbuf, float* __restrict__ out) {
    int i   = blockIdx.x * 256 + threadIdx.x;   // over B*C/4
    int row = i >> 8;                           // C/4 = 256 float4 per row
    int c4  = i & 255;
    const float4* s4 = (const float4*)sbuf;
    size_t b = (size_t)row * 3 * 256 + c4;
    float4 a = s4[b], d = s4[b + 256], g = s4[b + 512];
    float4 r;
    r.x = a.x + d.x + g.x; r.y = a.y + d.y + g.y;
    r.z = a.z + d.z + g.z; r.w = a.w + d.w + g.w;
    ((float4*)out)[i] = r;
}

extern "C" void kernel_launch(void* const* d_in, const int* in_sizes, int n_in,
                              void* d_out, int out_size, void* d_ws, size_t ws_size,
                              hipStream_t stream) {
    const float* x  = (const float*)d_in[0];
    const float* gW = (const float*)d_in[1];
    const float* gb = (const float*)d_in[2];
    const float* W1 = (const float*)d_in[3];
    const float* b1 = (const float*)d_in[4];
    const float* W2 = (const float*)d_in[5];
    const float* b2 = (const float*)d_in[6];
    float* out    = (float*)d_out;                 // [B, C]
    float* gw_out = out + (size_t)B_ * C_;         // [B, E]

    char* ws = (char*)d_ws;
    size_t off = 0;
    auto alloc = [&](size_t bytes) -> char* {
        char* p = ws + off;
        off = (off + bytes + 255) & ~(size_t)255;
        return p;
    };
    int*            counts  = (int*)alloc(E_ * 4);
    int*            rowlist = (int*)alloc((size_t)E_ * B_ * 4);
    float*          wtslist = (float*)alloc((size_t)E_ * B_ * 4);
    unsigned short* W2b     = (unsigned short*)alloc((size_t)E_ * C_ * H_ * 2);
    unsigned short* hbuf    = (unsigned short*)alloc((size_t)3 * B_ * H_ * 2);
    // union region: {xb + W1b} live until gemm1; sbuf live only gemm2+combine.
    size_t region_off = off;
    unsigned short* xb      = (unsigned short*)alloc((size_t)B_ * D_ * 2);
    unsigned short* W1b     = (unsigned short*)alloc((size_t)E_ * H_ * D_ * 2);
    float*          sbuf    = (float*)(ws + region_off);
    size_t sbuf_end = region_off + (size_t)3 * B_ * C_ * 4;
    bool use_sbuf = (ws_size == 0) || (sbuf_end <= ws_size);
    (void)in_sizes; (void)n_in; (void)out_size;

    hipMemsetAsync(counts, 0, E_ * 4, stream);
    if (!use_sbuf) hipMemsetAsync(out, 0, (size_t)B_ * C_ * 4, stream);

    gate_kernel<<<B_ / 4, 256, 0, stream>>>(x, gW, gb, gw_out, counts, rowlist, wtslist, xb);
    cast_f32_bf16<<<(E_ * H_ * D_ / 4) / 256, 256, 0, stream>>>(W1, W1b, E_ * H_ * D_ / 4);
    cast_f32_bf16<<<(E_ * C_ * H_ / 4) / 256, 256, 0, stream>>>(W2, W2b, E_ * C_ * H_ / 4);
    gemm1_kernel<<<dim3(8 * (B_ / 256), 1, E_), 512, 0, stream>>>(xb, W1b, b1, counts, rowlist, hbuf);
    gemm2_kernel<<<dim3(4 * (B_ / 256), 1, E_), 512, 0, stream>>>(hbuf, W2b, b2, counts, rowlist, wtslist,
                                                                  use_sbuf ? sbuf : (float*)nullptr, out);
    if (use_sbuf)
        combine_kernel<<<(B_ * C_ / 4) / 256, 256, 0, stream>>>(sbuf, out);
}

// Round 9
// 1764.338 us; speedup vs baseline: 1.1839x; 1.0614x over previous
//
#include <hip/hip_runtime.h>
#include <hip/hip_bf16.h>
#include <math.h>

#define B_ 16384
#define D_ 2048
#define H_ 2048
#define E_ 6
#define C_ 1024

#define HALF_ (128 * 64)   // elements per half-tile (128 rows x 64 k, bf16)

typedef __attribute__((ext_vector_type(8))) short short8;
typedef __attribute__((ext_vector_type(4))) float f32x4;

__device__ __forceinline__ unsigned short f2bf(float f) {
    __hip_bfloat16 h = __float2bfloat16(f);
    return *reinterpret_cast<unsigned short*>(&h);
}

__device__ __forceinline__ void async_copy16(const unsigned short* g, unsigned short* l) {
    __builtin_amdgcn_global_load_lds(
        (const __attribute__((address_space(1))) unsigned int*)(g),
        (__attribute__((address_space(3))) unsigned int*)(l), 16, 0, 0);
}

// ---------------- gate: fp64 logits, top-3, softmax, routing lists + fused x->bf16 cast ----------------
__global__ void gate_kernel(const float* __restrict__ x, const float* __restrict__ gW,
                            const float* __restrict__ gb, float* __restrict__ gw_out,
                            int* __restrict__ counts, int* __restrict__ rowlist,
                            float* __restrict__ wtslist, unsigned short* __restrict__ xb) {
    int wave = threadIdx.x >> 6;
    int lane = threadIdx.x & 63;
    int row  = blockIdx.x * 4 + wave;
    const float* xr = x + (size_t)row * D_;
    unsigned short* xbr = xb + (size_t)row * D_;
    double acc[E_] = {0, 0, 0, 0, 0, 0};
    for (int i = 0; i < D_ / 64; ++i) {
        int d = i * 64 + lane;
        float xf = xr[d];
        xbr[d] = f2bf(xf);
        double xv = (double)xf;
#pragma unroll
        for (int e = 0; e < E_; ++e) acc[e] += xv * (double)gW[e * D_ + d];
    }
#pragma unroll
    for (int off = 32; off > 0; off >>= 1) {
#pragma unroll
        for (int e = 0; e < E_; ++e) acc[e] += __shfl_down(acc[e], off);
    }
    if (lane == 0) {
        double lg[E_];
#pragma unroll
        for (int e = 0; e < E_; ++e) lg[e] = acc[e] + (double)gb[e];
        bool used[E_] = {false, false, false, false, false, false};
        int idx[3]; double val[3];
        for (int k = 0; k < 3; ++k) {
            int best = -1; double bv = -1e300;
            for (int e = 0; e < E_; ++e)
                if (!used[e] && lg[e] > bv) { bv = lg[e]; best = e; }
            used[best] = true; idx[k] = best; val[k] = bv;
        }
        double m = val[0];
        double w[3]; double s = 0.0;
        for (int k = 0; k < 3; ++k) { w[k] = exp(val[k] - m); s += w[k]; }
        float gwv[E_] = {0.f, 0.f, 0.f, 0.f, 0.f, 0.f};
        for (int k = 0; k < 3; ++k) gwv[idx[k]] = (float)(w[k] / s);
#pragma unroll
        for (int e = 0; e < E_; ++e) gw_out[(size_t)row * E_ + e] = gwv[e];
        for (int k = 0; k < 3; ++k) {
            int e = idx[k];
            int pos = atomicAdd(&counts[e], 1);
            rowlist[(size_t)e * B_ + pos] = row * 3 + k;   // global slot id
            wtslist[(size_t)e * B_ + pos] = (float)(w[k] / s);
        }
    }
}

// ---------------- f32 -> bf16 cast (vectorized) ----------------
__global__ void cast_f32_bf16(const float* __restrict__ in, unsigned short* __restrict__ out, int n4) {
    int i = blockIdx.x * blockDim.x + threadIdx.x;
    if (i < n4) {
        float4 v = ((const float4*)in)[i];
        ushort4 u;
        u.x = f2bf(v.x); u.y = f2bf(v.y); u.z = f2bf(v.z); u.w = f2bf(v.w);
        ((ushort4*)out)[i] = u;
    }
}

// =====================================================================
// 256x256 tile, BK=64, 8 waves (2M x 4N; per-wave 128x64), 2 K-tile LDS
// buffers (128 KiB).  DE-PHASED schedule: only the 3 correctness-required
// barriers per K-tile (pre-STAGE_B, pre-STAGE_A, tile boundary); between
// them, waves free-run so one wave's LDS waits overlap another's MFMA
// (m114 co-scheduling).  Counted vmcnt(8) boundary (T4): tile t+1 fenced,
// tile t+2's 8 stage-loads stay in flight; drains only in epilogue.
//
// Hazard proof: STAGE_B (issued after P2-barrier) needs all waves'
// B-reads done -- each wave passes P2-barrier only after its own
// lgkmcnt(0) for bQ(P1)/bR(P2) reads.  STAGE_A likewise after P3-barrier
// (A-reads in P1/P3 drained per-wave before arrival).  Boundary barrier +
// vmcnt(8) make tile t+1 visible before its reads.  All barriers
// followed by sched_barrier(0) so the machine scheduler cannot hoist
// VMEM stages above them (rule 18/21 discipline).
//
// LDS: per half [128][64] bf16, granule(16B)-XOR swizzle p^=(row&7)
// (0-conflict, verified rounds 0-6); staging pre-applies the inverse
// permutation on the GLOBAL source address (linear LDS dest).
// =====================================================================

#define STAGE_A(dstbuf, koff)                                                    \
    _Pragma("unroll")                                                            \
    for (int h_ = 0; h_ < 2; ++h_)                                               \
        _Pragma("unroll")                                                        \
        for (int j_ = 0; j_ < 2; ++j_)                                           \
            async_copy16(asrc[h_][j_] + (koff),                                  \
                         (dstbuf) + h_ * HALF_ + (j_ * 512 + tid) * 8);

#define STAGE_B(dstbuf, koff)                                                    \
    _Pragma("unroll")                                                            \
    for (int h_ = 0; h_ < 2; ++h_)                                               \
        _Pragma("unroll")                                                        \
        for (int j_ = 0; j_ < 2; ++j_)                                           \
            async_copy16(bsrc[h_][j_] + (koff),                                  \
                         (dstbuf) + h_ * HALF_ + (j_ * 512 + tid) * 8);

#define MFMA_BF16 __builtin_amdgcn_mfma_f32_16x16x32_bf16

#define LGKM0_FENCE()                                                            \
    asm volatile("s_waitcnt lgkmcnt(0)" ::: "memory");                           \
    __builtin_amdgcn_sched_barrier(0);

#define BARRIER_FENCE()                                                          \
    __builtin_amdgcn_s_barrier();                                                \
    __builtin_amdgcn_sched_barrier(0);

#define GEMM_CORE(KDIM)                                                          \
    int lane = tid & 63;                                                         \
    int wv = tid >> 6;                                                           \
    int wr = wv >> 2;   /* 0..1: M half   */                                     \
    int wc = wv & 3;    /* 0..3: N strip  */                                     \
    int fm = lane & 15;                                                          \
    int kg = lane >> 4;                                                          \
    unsigned g0 = (unsigned)((kg ^ (fm & 7)) * 8);                               \
    unsigned g1 = (unsigned)(((4 + kg) ^ (fm & 7)) * 8);                         \
    unsigned aRB = (unsigned)(wr * HALF_ + fm * 64);                             \
    unsigned bRB = (unsigned)((wc >> 1) * HALF_ + ((wc & 1) * 64 + fm) * 64);    \
    f32x4 acc[8][4] = {};                                                        \
    const int NT = (KDIM) / 64;                                                  \
    STAGE_A(As, 0) STAGE_B(Bs, 0)                                                \
    STAGE_A(As + 2 * HALF_, 64) STAGE_B(Bs + 2 * HALF_, 64)                      \
    asm volatile("s_waitcnt vmcnt(8)" ::: "memory");                             \
    BARRIER_FENCE()                                                              \
    for (int t = 0; t < NT; ++t) {                                               \
        unsigned short* Ab = As + (t & 1) * (2 * HALF_);                         \
        unsigned short* Bb = Bs + (t & 1) * (2 * HALF_);                         \
        const bool st = (t + 2 < NT);                                            \
        const int koff = (t + 2) * 64;                                           \
        const unsigned short* Ar0 = Ab + aRB + g0;                               \
        const unsigned short* Ar1 = Ab + aRB + g1;                               \
        const unsigned short* Br0 = Bb + bRB + g0;                               \
        const unsigned short* Br1 = Bb + bRB + g1;                               \
        short8 aF[4][2], bQ[2][2], bR[2][2];                                     \
        /* -- P1: read A(m0-3)+B(n0-1); MFMA (m0-3 x n0-1). no barrier -- */     \
        _Pragma("unroll")                                                        \
        for (int m = 0; m < 4; ++m) {                                            \
            aF[m][0] = *(const short8*)(Ar0 + m * 1024);                         \
            aF[m][1] = *(const short8*)(Ar1 + m * 1024);                         \
        }                                                                        \
        _Pragma("unroll")                                                        \
        for (int n = 0; n < 2; ++n) {                                            \
            bQ[n][0] = *(const short8*)(Br0 + n * 1024);                         \
            bQ[n][1] = *(const short8*)(Br1 + n * 1024);                         \
        }                                                                        \
        LGKM0_FENCE()                                                            \
        __builtin_amdgcn_s_setprio(1);                                           \
        _Pragma("unroll")                                                        \
        for (int m = 0; m < 4; ++m)                                              \
            _Pragma("unroll")                                                    \
            for (int n = 0; n < 2; ++n) {                                        \
                acc[m][n] = MFMA_BF16(aF[m][0], bQ[n][0], acc[m][n], 0, 0, 0);   \
                acc[m][n] = MFMA_BF16(aF[m][1], bQ[n][1], acc[m][n], 0, 0, 0);   \
            }                                                                    \
        __builtin_amdgcn_s_setprio(0);                                           \
        /* -- P2: read B(n2-3); barrier (B-reads done CU-wide); MFMA -- */       \
        _Pragma("unroll")                                                        \
        for (int n = 0; n < 2; ++n) {                                            \
            bR[n][0] = *(const short8*)(Br0 + (2 + n) * 1024);                   \
            bR[n][1] = *(const short8*)(Br1 + (2 + n) * 1024);                   \
        }                                                                        \
        LGKM0_FENCE()                                                            \
        BARRIER_FENCE()                                                          \
        __builtin_amdgcn_s_setprio(1);                                           \
        _Pragma("unroll")                                                        \
        for (int m = 0; m < 4; ++m)                                              \
            _Pragma("unroll")                                                    \
            for (int n = 0; n < 2; ++n) {                                        \
                acc[m][2 + n] = MFMA_BF16(aF[m][0], bR[n][0], acc[m][2 + n], 0, 0, 0); \
                acc[m][2 + n] = MFMA_BF16(aF[m][1], bR[n][1], acc[m][2 + n], 0, 0, 0); \
            }                                                                    \
        __builtin_amdgcn_s_setprio(0);                                           \
        /* -- P3: stage B(t+2); read A(m4-7); barrier (A-reads done); MFMA -- */ \
        if (st) { STAGE_B(Bb, koff) }                                            \
        _Pragma("unroll")                                                        \
        for (int m = 0; m < 4; ++m) {                                            \
            aF[m][0] = *(const short8*)(Ar0 + (4 + m) * 1024);                   \
            aF[m][1] = *(const short8*)(Ar1 + (4 + m) * 1024);                   \
        }                                                                        \
        LGKM0_FENCE()                                                            \
        BARRIER_FENCE()                                                          \
        __builtin_amdgcn_s_setprio(1);                                           \
        _Pragma("unroll")                                                        \
        for (int m = 0; m < 4; ++m)                                              \
            _Pragma("unroll")                                                    \
            for (int n = 0; n < 2; ++n) {                                        \
                acc[4 + m][n] = MFMA_BF16(aF[m][0], bQ[n][0], acc[4 + m][n], 0, 0, 0); \
                acc[4 + m][n] = MFMA_BF16(aF[m][1], bQ[n][1], acc[4 + m][n], 0, 0, 0); \
            }                                                                    \
        __builtin_amdgcn_s_setprio(0);                                           \
        /* -- P4: stage A(t+2); MFMA (m4-7 x n2-3); boundary vmcnt+barrier -- */ \
        if (st) { STAGE_A(Ab, koff) }                                            \
        __builtin_amdgcn_s_setprio(1);                                           \
        _Pragma("unroll")                                                        \
        for (int m = 0; m < 4; ++m)                                              \
            _Pragma("unroll")                                                    \
            for (int n = 0; n < 2; ++n) {                                        \
                acc[4 + m][2 + n] = MFMA_BF16(aF[m][0], bR[n][0], acc[4 + m][2 + n], 0, 0, 0); \
                acc[4 + m][2 + n] = MFMA_BF16(aF[m][1], bR[n][1], acc[4 + m][2 + n], 0, 0, 0); \
            }                                                                    \
        __builtin_amdgcn_s_setprio(0);                                           \
        __builtin_amdgcn_sched_barrier(0);                                       \
        if (st) asm volatile("s_waitcnt vmcnt(8)" ::: "memory");                 \
        else    asm volatile("s_waitcnt vmcnt(0)" ::: "memory");                 \
        __builtin_amdgcn_sched_barrier(0);                                       \
        BARRIER_FENCE()                                                          \
    }

// ---------------- GEMM1: hbuf[compact] = gelu(x[row] @ W1[e]^T + b1[e]) ----------------
__global__ __launch_bounds__(512, 2) void gemm1_kernel(
    const unsigned short* __restrict__ xb, const unsigned short* __restrict__ W1b,
    const float* __restrict__ b1, const int* __restrict__ counts,
    const int* __restrict__ rowlist, unsigned short* __restrict__ hbuf) {
    int e = blockIdx.z;
    int cnt = counts[e];
    int eoff = 0;
#pragma unroll
    for (int i = 0; i < E_; ++i) if (i < e) eoff += counts[i];   // compact prefix
    // XCD-panel rasterization: the 8 n-blocks of an m-panel land on one XCD
    int flat = blockIdx.x;                      // grid.x = 8 * 64 = 512
    int p  = (flat & 7) + ((flat >> 6) << 3);   // m-panel 0..63
    int nb = (flat >> 3) & 7;                   // n-block 0..7
    int m0 = p * 256;
    if (m0 >= cnt) return;
    int n0 = nb * 256;

    __shared__ __align__(16) unsigned short As[4 * HALF_];   // 64 KiB
    __shared__ __align__(16) unsigned short Bs[4 * HALF_];   // 64 KiB
    int tid = threadIdx.x;
    const int* rlist = rowlist + (size_t)e * B_;

    // staging source pointers: thread owns granule (rb, gth) of each half
    int rb = tid >> 3;
    int gth = ((tid & 7) ^ (rb & 7)) * 8;
    const unsigned short* asrc[2][2];
    const unsigned short* bsrc[2][2];
#pragma unroll
    for (int h = 0; h < 2; ++h)
#pragma unroll
        for (int j = 0; j < 2; ++j) {
            int r = h * 128 + j * 64 + rb;
            int idx = m0 + r; if (idx >= cnt) idx = cnt - 1;
            asrc[h][j] = xb + (size_t)(rlist[idx] / 3) * D_ + gth;
            bsrc[h][j] = W1b + (size_t)e * H_ * D_ + (size_t)(n0 + r) * D_ + gth;
        }

    GEMM_CORE(D_)

    int rlim = cnt - m0;
#pragma unroll
    for (int m = 0; m < 8; ++m) {
#pragma unroll
        for (int i = 0; i < 4; ++i) {
            int r = wr * 128 + m * 16 + kg * 4 + i;
            if (r < rlim) {
                size_t base = (size_t)(eoff + m0 + r) * H_ + n0;   // compact row
#pragma unroll
                for (int n = 0; n < 4; ++n) {
                    int col = wc * 64 + n * 16 + fm;
                    float v = acc[m][n][i] + b1[e * H_ + n0 + col];
                    v = 0.5f * v * (1.0f + erff(v * 0.70710678118654752f)); // exact GELU
                    __builtin_nontemporal_store(f2bf(v), &hbuf[base + col]);
                }
            }
        }
    }
}

// ---------------- GEMM2: sbuf[slot] = w * (hbuf[compact] @ W2[e]^T + b2[e]) ----------------
__global__ __launch_bounds__(512, 2) void gemm2_kernel(
    const unsigned short* __restrict__ hbuf, const unsigned short* __restrict__ W2b,
    const float* __restrict__ b2, const int* __restrict__ counts,
    const int* __restrict__ rowlist, const float* __restrict__ wtslist,
    float* __restrict__ sbuf, float* __restrict__ out) {
    int e = blockIdx.z;
    int cnt = counts[e];
    int eoff = 0;
#pragma unroll
    for (int i = 0; i < E_; ++i) if (i < e) eoff += counts[i];
    int flat = blockIdx.x;                      // grid.x = 4 * 64 = 256
    int p  = (flat & 7) + ((flat >> 5) << 3);   // m-panel 0..63
    int nb = (flat >> 3) & 3;                   // n-block 0..3
    int m0 = p * 256;
    if (m0 >= cnt) return;
    int n0 = nb * 256;

    __shared__ __align__(16) unsigned short As[4 * HALF_];
    __shared__ __align__(16) unsigned short Bs[4 * HALF_];
    int tid = threadIdx.x;
    const int* rlist = rowlist + (size_t)e * B_;
    const float* wlist = wtslist + (size_t)e * B_;

    int rb = tid >> 3;
    int gth = ((tid & 7) ^ (rb & 7)) * 8;
    const unsigned short* asrc[2][2];
    const unsigned short* bsrc[2][2];
#pragma unroll
    for (int h = 0; h < 2; ++h)
#pragma unroll
        for (int j = 0; j < 2; ++j) {
            int r = h * 128 + j * 64 + rb;
            int idx = m0 + r; if (idx >= cnt) idx = cnt - 1;
            asrc[h][j] = hbuf + (size_t)(eoff + idx) * H_ + gth;   // contiguous compact rows
            bsrc[h][j] = W2b + (size_t)e * C_ * H_ + (size_t)(n0 + r) * H_ + gth;
        }

    GEMM_CORE(H_)

    int rlim = cnt - m0;
#pragma unroll
    for (int m = 0; m < 8; ++m) {
#pragma unroll
        for (int i = 0; i < 4; ++i) {
            int r = wr * 128 + m * 16 + kg * 4 + i;
            if (r < rlim) {
                int slot = rlist[m0 + r];
                float w  = wlist[m0 + r];
                if (sbuf) {
                    float* srow = sbuf + (size_t)slot * C_ + n0;   // exclusive ownership
#pragma unroll
                    for (int n = 0; n < 4; ++n) {
                        int col = wc * 64 + n * 16 + fm;
                        __builtin_nontemporal_store(
                            (acc[m][n][i] + b2[e * C_ + n0 + col]) * w, &srow[col]);
                    }
                } else {
                    float* orow = out + (size_t)(slot / 3) * C_ + n0;
#pragma unroll
                    for (int n = 0; n < 4; ++n) {
                        int col = wc * 64 + n * 16 + fm;
                        atomicAdd(&orow[col], (acc[m][n][i] + b2[e * C_ + n0 + col]) * w);
                    }
                }
            }
        }
    }
}

// ---------------- combine: out[row] = sum of the row's 3 slot rows ----------------
__global__ void combine_kernel(const float* __restrict__ sbuf, float* __restrict__ out) {
    int i   = blockIdx.x * 256 + threadIdx.x;   // over B*C/4
    int row = i >> 8;                           // C/4 = 256 f32x4 per row
    int c4  = i & 255;
    const f32x4* s4 = (const f32x4*)sbuf;
    size_t b = (size_t)row * 3 * 256 + c4;
    f32x4 a = __builtin_nontemporal_load(&s4[b]);
    f32x4 d = __builtin_nontemporal_load(&s4[b + 256]);
    f32x4 g = __builtin_nontemporal_load(&s4[b + 512]);
    f32x4 r = a + d + g;
    __builtin_nontemporal_store(r, &((f32x4*)out)[i]);
}

extern "C" void kernel_launch(void* const* d_in, const int* in_sizes, int n_in,
                              void* d_out, int out_size, void* d_ws, size_t ws_size,
                              hipStream_t stream) {
    const float* x  = (const float*)d_in[0];
    const float* gW = (const float*)d_in[1];
    const float* gb = (const float*)d_in[2];
    const float* W1 = (const float*)d_in[3];
    const float* b1 = (const float*)d_in[4];
    const float* W2 = (const float*)d_in[5];
    const float* b2 = (const float*)d_in[6];
    float* out    = (float*)d_out;                 // [B, C]
    float* gw_out = out + (size_t)B_ * C_;         // [B, E]

    char* ws = (char*)d_ws;
    size_t off = 0;
    auto alloc = [&](size_t bytes) -> char* {
        char* p = ws + off;
        off = (off + bytes + 255) & ~(size_t)255;
        return p;
    };
    int*            counts  = (int*)alloc(E_ * 4);
    int*            rowlist = (int*)alloc((size_t)E_ * B_ * 4);
    float*          wtslist = (float*)alloc((size_t)E_ * B_ * 4);
    unsigned short* W2b     = (unsigned short*)alloc((size_t)E_ * C_ * H_ * 2);
    unsigned short* hbuf    = (unsigned short*)alloc((size_t)3 * B_ * H_ * 2);
    // union region: {xb + W1b} live until gemm1; sbuf live only gemm2+combine.
    size_t region_off = off;
    unsigned short* xb      = (unsigned short*)alloc((size_t)B_ * D_ * 2);
    unsigned short* W1b     = (unsigned short*)alloc((size_t)E_ * H_ * D_ * 2);
    float*          sbuf    = (float*)(ws + region_off);
    size_t sbuf_end = region_off + (size_t)3 * B_ * C_ * 4;
    bool use_sbuf = (ws_size == 0) || (sbuf_end <= ws_size);
    (void)in_sizes; (void)n_in; (void)out_size;

    hipMemsetAsync(counts, 0, E_ * 4, stream);
    if (!use_sbuf) hipMemsetAsync(out, 0, (size_t)B_ * C_ * 4, stream);

    gate_kernel<<<B_ / 4, 256, 0, stream>>>(x, gW, gb, gw_out, counts, rowlist, wtslist, xb);
    cast_f32_bf16<<<(E_ * H_ * D_ / 4) / 256, 256, 0, stream>>>(W1, W1b, E_ * H_ * D_ / 4);
    cast_f32_bf16<<<(E_ * C_ * H_ / 4) / 256, 256, 0, stream>>>(W2, W2b, E_ * C_ * H_ / 4);
    gemm1_kernel<<<dim3(8 * (B_ / 256), 1, E_), 512, 0, stream>>>(xb, W1b, b1, counts, rowlist, hbuf);
    gemm2_kernel<<<dim3(4 * (B_ / 256), 1, E_), 512, 0, stream>>>(hbuf, W2b, b2, counts, rowlist, wtslist,
                                                                  use_sbuf ? sbuf : (float*)nullptr, out);
    if (use_sbuf)
        combine_kernel<<<(B_ * C_ / 4) / 256, 256, 0, stream>>>(sbuf, out);
}

// Round 10
// 1756.906 us; speedup vs baseline: 1.1889x; 1.0042x over previous
//
#include <hip/hip_runtime.h>
#include <hip/hip_bf16.h>
#include <hip/hip_fp16.h>
#include <math.h>

#define B_ 16384
#define D_ 2048
#define H_ 2048
#define E_ 6
#define C_ 1024

#define HALF_ (128 * 64)   // elements per half-tile (128 rows x 64 k, bf16)

typedef __attribute__((ext_vector_type(8))) short short8;
typedef __attribute__((ext_vector_type(4))) float f32x4;

__device__ __forceinline__ unsigned short f2bf(float f) {
    __hip_bfloat16 h = __float2bfloat16(f);
    return *reinterpret_cast<unsigned short*>(&h);
}

__device__ __forceinline__ unsigned short f2h(float f) {
    __half h = __float2half(f);
    return *reinterpret_cast<unsigned short*>(&h);
}

__device__ __forceinline__ float h2f(unsigned short u) {
    __half h = *reinterpret_cast<__half*>(&u);
    return __half2float(h);
}

__device__ __forceinline__ void async_copy16(const unsigned short* g, unsigned short* l) {
    __builtin_amdgcn_global_load_lds(
        (const __attribute__((address_space(1))) unsigned int*)(g),
        (__attribute__((address_space(3))) unsigned int*)(l), 16, 0, 0);
}

// ---------------- gate: fp64 logits, top-3, softmax, routing lists + fused x->bf16 cast ----------------
__global__ void gate_kernel(const float* __restrict__ x, const float* __restrict__ gW,
                            const float* __restrict__ gb, float* __restrict__ gw_out,
                            int* __restrict__ counts, int* __restrict__ rowlist,
                            float* __restrict__ wtslist, unsigned short* __restrict__ xb) {
    int wave = threadIdx.x >> 6;
    int lane = threadIdx.x & 63;
    int row  = blockIdx.x * 4 + wave;
    const float* xr = x + (size_t)row * D_;
    unsigned short* xbr = xb + (size_t)row * D_;
    double acc[E_] = {0, 0, 0, 0, 0, 0};
    for (int i = 0; i < D_ / 64; ++i) {
        int d = i * 64 + lane;
        float xf = xr[d];
        xbr[d] = f2bf(xf);
        double xv = (double)xf;
#pragma unroll
        for (int e = 0; e < E_; ++e) acc[e] += xv * (double)gW[e * D_ + d];
    }
#pragma unroll
    for (int off = 32; off > 0; off >>= 1) {
#pragma unroll
        for (int e = 0; e < E_; ++e) acc[e] += __shfl_down(acc[e], off);
    }
    if (lane == 0) {
        double lg[E_];
#pragma unroll
        for (int e = 0; e < E_; ++e) lg[e] = acc[e] + (double)gb[e];
        bool used[E_] = {false, false, false, false, false, false};
        int idx[3]; double val[3];
        for (int k = 0; k < 3; ++k) {
            int best = -1; double bv = -1e300;
            for (int e = 0; e < E_; ++e)
                if (!used[e] && lg[e] > bv) { bv = lg[e]; best = e; }
            used[best] = true; idx[k] = best; val[k] = bv;
        }
        double m = val[0];
        double w[3]; double s = 0.0;
        for (int k = 0; k < 3; ++k) { w[k] = exp(val[k] - m); s += w[k]; }
        float gwv[E_] = {0.f, 0.f, 0.f, 0.f, 0.f, 0.f};
        for (int k = 0; k < 3; ++k) gwv[idx[k]] = (float)(w[k] / s);
#pragma unroll
        for (int e = 0; e < E_; ++e) gw_out[(size_t)row * E_ + e] = gwv[e];
        for (int k = 0; k < 3; ++k) {
            int e = idx[k];
            int pos = atomicAdd(&counts[e], 1);
            rowlist[(size_t)e * B_ + pos] = row * 3 + k;   // global slot id
            wtslist[(size_t)e * B_ + pos] = (float)(w[k] / s);
        }
    }
}

// ---------------- f32 -> bf16 cast (vectorized) ----------------
__global__ void cast_f32_bf16(const float* __restrict__ in, unsigned short* __restrict__ out, int n4) {
    int i = blockIdx.x * blockDim.x + threadIdx.x;
    if (i < n4) {
        float4 v = ((const float4*)in)[i];
        ushort4 u;
        u.x = f2bf(v.x); u.y = f2bf(v.y); u.z = f2bf(v.z); u.w = f2bf(v.w);
        ((ushort4*)out)[i] = u;
    }
}

// =====================================================================
// 256x256 tile, BK=64, 8 waves (2M x 4N; per-wave 128x64), 2 K-tile LDS
// buffers (128 KiB).  DE-PHASED schedule (round-9, measured best): only
// the 3 correctness-required barriers per K-tile (pre-STAGE_B,
// pre-STAGE_A, tile boundary); between them waves free-run so one wave's
// LDS waits overlap another's MFMA.  Counted vmcnt(8) boundary (T4):
// tile t+1 fenced, tile t+2's 8 stage-loads stay in flight; drains only
// in epilogue.  All inline s_waitcnt followed by sched_barrier(0).
//
// LDS: per half [128][64] bf16, granule(16B)-XOR swizzle p^=(row&7)
// (0-conflict, verified rounds 0-9); staging pre-applies the inverse
// permutation on the GLOBAL source address (linear LDS dest).
// =====================================================================

#define STAGE_A(dstbuf, koff)                                                    \
    _Pragma("unroll")                                                            \
    for (int h_ = 0; h_ < 2; ++h_)                                               \
        _Pragma("unroll")                                                        \
        for (int j_ = 0; j_ < 2; ++j_)                                           \
            async_copy16(asrc[h_][j_] + (koff),                                  \
                         (dstbuf) + h_ * HALF_ + (j_ * 512 + tid) * 8);

#define STAGE_B(dstbuf, koff)                                                    \
    _Pragma("unroll")                                                            \
    for (int h_ = 0; h_ < 2; ++h_)                                               \
        _Pragma("unroll")                                                        \
        for (int j_ = 0; j_ < 2; ++j_)                                           \
            async_copy16(bsrc[h_][j_] + (koff),                                  \
                         (dstbuf) + h_ * HALF_ + (j_ * 512 + tid) * 8);

#define MFMA_BF16 __builtin_amdgcn_mfma_f32_16x16x32_bf16

#define LGKM0_FENCE()                                                            \
    asm volatile("s_waitcnt lgkmcnt(0)" ::: "memory");                           \
    __builtin_amdgcn_sched_barrier(0);

#define BARRIER_FENCE()                                                          \
    __builtin_amdgcn_s_barrier();                                                \
    __builtin_amdgcn_sched_barrier(0);

#define GEMM_CORE(KDIM)                                                          \
    int lane = tid & 63;                                                         \
    int wv = tid >> 6;                                                           \
    int wr = wv >> 2;   /* 0..1: M half   */                                     \
    int wc = wv & 3;    /* 0..3: N strip  */                                     \
    int fm = lane & 15;                                                          \
    int kg = lane >> 4;                                                          \
    unsigned g0 = (unsigned)((kg ^ (fm & 7)) * 8);                               \
    unsigned g1 = (unsigned)(((4 + kg) ^ (fm & 7)) * 8);                         \
    unsigned aRB = (unsigned)(wr * HALF_ + fm * 64);                             \
    unsigned bRB = (unsigned)((wc >> 1) * HALF_ + ((wc & 1) * 64 + fm) * 64);    \
    f32x4 acc[8][4] = {};                                                        \
    const int NT = (KDIM) / 64;                                                  \
    STAGE_A(As, 0) STAGE_B(Bs, 0)                                                \
    STAGE_A(As + 2 * HALF_, 64) STAGE_B(Bs + 2 * HALF_, 64)                      \
    asm volatile("s_waitcnt vmcnt(8)" ::: "memory");                             \
    BARRIER_FENCE()                                                              \
    for (int t = 0; t < NT; ++t) {                                               \
        unsigned short* Ab = As + (t & 1) * (2 * HALF_);                         \
        unsigned short* Bb = Bs + (t & 1) * (2 * HALF_);                         \
        const bool st = (t + 2 < NT);                                            \
        const int koff = (t + 2) * 64;                                           \
        const unsigned short* Ar0 = Ab + aRB + g0;                               \
        const unsigned short* Ar1 = Ab + aRB + g1;                               \
        const unsigned short* Br0 = Bb + bRB + g0;                               \
        const unsigned short* Br1 = Bb + bRB + g1;                               \
        short8 aF[4][2], bQ[2][2], bR[2][2];                                     \
        /* -- P1: read A(m0-3)+B(n0-1); MFMA (m0-3 x n0-1). no barrier -- */     \
        _Pragma("unroll")                                                        \
        for (int m = 0; m < 4; ++m) {                                            \
            aF[m][0] = *(const short8*)(Ar0 + m * 1024);                         \
            aF[m][1] = *(const short8*)(Ar1 + m * 1024);                         \
        }                                                                        \
        _Pragma("unroll")                                                        \
        for (int n = 0; n < 2; ++n) {                                            \
            bQ[n][0] = *(const short8*)(Br0 + n * 1024);                         \
            bQ[n][1] = *(const short8*)(Br1 + n * 1024);                         \
        }                                                                        \
        LGKM0_FENCE()                                                            \
        __builtin_amdgcn_s_setprio(1);                                           \
        _Pragma("unroll")                                                        \
        for (int m = 0; m < 4; ++m)                                              \
            _Pragma("unroll")                                                    \
            for (int n = 0; n < 2; ++n) {                                        \
                acc[m][n] = MFMA_BF16(aF[m][0], bQ[n][0], acc[m][n], 0, 0, 0);   \
                acc[m][n] = MFMA_BF16(aF[m][1], bQ[n][1], acc[m][n], 0, 0, 0);   \
            }                                                                    \
        __builtin_amdgcn_s_setprio(0);                                           \
        /* -- P2: read B(n2-3); barrier (B-reads done CU-wide); MFMA -- */       \
        _Pragma("unroll")                                                        \
        for (int n = 0; n < 2; ++n) {                                            \
            bR[n][0] = *(const short8*)(Br0 + (2 + n) * 1024);                   \
            bR[n][1] = *(const short8*)(Br1 + (2 + n) * 1024);                   \
        }                                                                        \
        LGKM0_FENCE()                                                            \
        BARRIER_FENCE()                                                          \
        __builtin_amdgcn_s_setprio(1);                                           \
        _Pragma("unroll")                                                        \
        for (int m = 0; m < 4; ++m)                                              \
            _Pragma("unroll")                                                    \
            for (int n = 0; n < 2; ++n) {                                        \
                acc[m][2 + n] = MFMA_BF16(aF[m][0], bR[n][0], acc[m][2 + n], 0, 0, 0); \
                acc[m][2 + n] = MFMA_BF16(aF[m][1], bR[n][1], acc[m][2 + n], 0, 0, 0); \
            }                                                                    \
        __builtin_amdgcn_s_setprio(0);                                           \
        /* -- P3: stage B(t+2); read A(m4-7); barrier (A-reads done); MFMA -- */ \
        if (st) { STAGE_B(Bb, koff) }                                            \
        _Pragma("unroll")                                                        \
        for (int m = 0; m < 4; ++m) {                                            \
            aF[m][0] = *(const short8*)(Ar0 + (4 + m) * 1024);                   \
            aF[m][1] = *(const short8*)(Ar1 + (4 + m) * 1024);                   \
        }                                                                        \
        LGKM0_FENCE()                                                            \
        BARRIER_FENCE()                                                          \
        __builtin_amdgcn_s_setprio(1);                                           \
        _Pragma("unroll")                                                        \
        for (int m = 0; m < 4; ++m)                                              \
            _Pragma("unroll")                                                    \
            for (int n = 0; n < 2; ++n) {                                        \
                acc[4 + m][n] = MFMA_BF16(aF[m][0], bQ[n][0], acc[4 + m][n], 0, 0, 0); \
                acc[4 + m][n] = MFMA_BF16(aF[m][1], bQ[n][1], acc[4 + m][n], 0, 0, 0); \
            }                                                                    \
        __builtin_amdgcn_s_setprio(0);                                           \
        /* -- P4: stage A(t+2); MFMA (m4-7 x n2-3); boundary vmcnt+barrier -- */ \
        if (st) { STAGE_A(Ab, koff) }                                            \
        __builtin_amdgcn_s_setprio(1);                                           \
        _Pragma("unroll")                                                        \
        for (int m = 0; m < 4; ++m)                                              \
            _Pragma("unroll")                                                    \
            for (int n = 0; n < 2; ++n) {                                        \
                acc[4 + m][2 + n] = MFMA_BF16(aF[m][0], bR[n][0], acc[4 + m][2 + n], 0, 0, 0); \
                acc[4 + m][2 + n] = MFMA_BF16(aF[m][1], bR[n][1], acc[4 + m][2 + n], 0, 0, 0); \
            }                                                                    \
        __builtin_amdgcn_s_setprio(0);                                           \
        __builtin_amdgcn_sched_barrier(0);                                       \
        if (st) asm volatile("s_waitcnt vmcnt(8)" ::: "memory");                 \
        else    asm volatile("s_waitcnt vmcnt(0)" ::: "memory");                 \
        __builtin_amdgcn_sched_barrier(0);                                       \
        BARRIER_FENCE()                                                          \
    }

// ---------------- GEMM1: hbuf[compact] = gelu(x[row] @ W1[e]^T + b1[e]) ----------------
__global__ __launch_bounds__(512, 2) void gemm1_kernel(
    const unsigned short* __restrict__ xb, const unsigned short* __restrict__ W1b,
    const float* __restrict__ b1, const int* __restrict__ counts,
    const int* __restrict__ rowlist, unsigned short* __restrict__ hbuf) {
    int e = blockIdx.z;
    int cnt = counts[e];
    int eoff = 0;
#pragma unroll
    for (int i = 0; i < E_; ++i) if (i < e) eoff += counts[i];   // compact prefix
    // XCD-panel rasterization: the 8 n-blocks of an m-panel land on one XCD
    int flat = blockIdx.x;                      // grid.x = 8 * 64 = 512
    int p  = (flat & 7) + ((flat >> 6) << 3);   // m-panel 0..63
    int nb = (flat >> 3) & 7;                   // n-block 0..7
    int m0 = p * 256;
    if (m0 >= cnt) return;
    int n0 = nb * 256;

    __shared__ __align__(16) unsigned short As[4 * HALF_];   // 64 KiB
    __shared__ __align__(16) unsigned short Bs[4 * HALF_];   // 64 KiB
    int tid = threadIdx.x;
    const int* rlist = rowlist + (size_t)e * B_;

    // staging source pointers: thread owns granule (rb, gth) of each half
    int rb = tid >> 3;
    int gth = ((tid & 7) ^ (rb & 7)) * 8;
    const unsigned short* asrc[2][2];
    const unsigned short* bsrc[2][2];
#pragma unroll
    for (int h = 0; h < 2; ++h)
#pragma unroll
        for (int j = 0; j < 2; ++j) {
            int r = h * 128 + j * 64 + rb;
            int idx = m0 + r; if (idx >= cnt) idx = cnt - 1;
            asrc[h][j] = xb + (size_t)(rlist[idx] / 3) * D_ + gth;
            bsrc[h][j] = W1b + (size_t)e * H_ * D_ + (size_t)(n0 + r) * D_ + gth;
        }

    GEMM_CORE(D_)

    int rlim = cnt - m0;
#pragma unroll
    for (int m = 0; m < 8; ++m) {
#pragma unroll
        for (int i = 0; i < 4; ++i) {
            int r = wr * 128 + m * 16 + kg * 4 + i;
            if (r < rlim) {
                size_t base = (size_t)(eoff + m0 + r) * H_ + n0;   // compact row
#pragma unroll
                for (int n = 0; n < 4; ++n) {
                    int col = wc * 64 + n * 16 + fm;
                    float v = acc[m][n][i] + b1[e * H_ + n0 + col];
                    v = 0.5f * v * (1.0f + erff(v * 0.70710678118654752f)); // exact GELU
                    hbuf[base + col] = f2bf(v);   // regular store: L2 write-combining
                }
            }
        }
    }
}

// ---------------- GEMM2: sbuf16[slot] = f16(w * (hbuf[compact] @ W2[e]^T + b2[e])) ----------------
__global__ __launch_bounds__(512, 2) void gemm2_kernel(
    const unsigned short* __restrict__ hbuf, const unsigned short* __restrict__ W2b,
    const float* __restrict__ b2, const int* __restrict__ counts,
    const int* __restrict__ rowlist, const float* __restrict__ wtslist,
    unsigned short* __restrict__ sbuf, float* __restrict__ out) {
    int e = blockIdx.z;
    int cnt = counts[e];
    int eoff = 0;
#pragma unroll
    for (int i = 0; i < E_; ++i) if (i < e) eoff += counts[i];
    int flat = blockIdx.x;                      // grid.x = 4 * 64 = 256
    int p  = (flat & 7) + ((flat >> 5) << 3);   // m-panel 0..63
    int nb = (flat >> 3) & 3;                   // n-block 0..3
    int m0 = p * 256;
    if (m0 >= cnt) return;
    int n0 = nb * 256;

    __shared__ __align__(16) unsigned short As[4 * HALF_];
    __shared__ __align__(16) unsigned short Bs[4 * HALF_];
    int tid = threadIdx.x;
    const int* rlist = rowlist + (size_t)e * B_;
    const float* wlist = wtslist + (size_t)e * B_;

    int rb = tid >> 3;
    int gth = ((tid & 7) ^ (rb & 7)) * 8;
    const unsigned short* asrc[2][2];
    const unsigned short* bsrc[2][2];
#pragma unroll
    for (int h = 0; h < 2; ++h)
#pragma unroll
        for (int j = 0; j < 2; ++j) {
            int r = h * 128 + j * 64 + rb;
            int idx = m0 + r; if (idx >= cnt) idx = cnt - 1;
            asrc[h][j] = hbuf + (size_t)(eoff + idx) * H_ + gth;   // contiguous compact rows
            bsrc[h][j] = W2b + (size_t)e * C_ * H_ + (size_t)(n0 + r) * H_ + gth;
        }

    GEMM_CORE(H_)

    int rlim = cnt - m0;
#pragma unroll
    for (int m = 0; m < 8; ++m) {
#pragma unroll
        for (int i = 0; i < 4; ++i) {
            int r = wr * 128 + m * 16 + kg * 4 + i;
            if (r < rlim) {
                int slot = rlist[m0 + r];
                float w  = wlist[m0 + r];
                if (sbuf) {
                    unsigned short* srow = sbuf + (size_t)slot * C_ + n0;  // exclusive ownership
#pragma unroll
                    for (int n = 0; n < 4; ++n) {
                        int col = wc * 64 + n * 16 + fm;
                        srow[col] = f2h((acc[m][n][i] + b2[e * C_ + n0 + col]) * w);
                    }
                } else {
                    float* orow = out + (size_t)(slot / 3) * C_ + n0;
#pragma unroll
                    for (int n = 0; n < 4; ++n) {
                        int col = wc * 64 + n * 16 + fm;
                        atomicAdd(&orow[col], (acc[m][n][i] + b2[e * C_ + n0 + col]) * w);
                    }
                }
            }
        }
    }
}

// ---------------- combine: out[row] = sum of the row's 3 f16 slot rows (f32 accum) ----------------
__global__ void combine_kernel(const unsigned short* __restrict__ sbuf, float* __restrict__ out) {
    int i   = blockIdx.x * 256 + threadIdx.x;   // over B*C/8
    int row = i >> 7;                           // C/8 = 128 short8 per row
    int c8  = i & 127;
    const short8* s8 = (const short8*)sbuf;
    size_t b = (size_t)row * 3 * 128 + c8;
    short8 a = s8[b], d = s8[b + 128], g = s8[b + 256];
    f32x4 lo, hi;
#pragma unroll
    for (int j = 0; j < 4; ++j) {
        lo[j] = h2f((unsigned short)a[j]) + h2f((unsigned short)d[j]) + h2f((unsigned short)g[j]);
        hi[j] = h2f((unsigned short)a[4 + j]) + h2f((unsigned short)d[4 + j]) + h2f((unsigned short)g[4 + j]);
    }
    f32x4* o4 = (f32x4*)(out + (size_t)i * 8);
    __builtin_nontemporal_store(lo, &o4[0]);
    __builtin_nontemporal_store(hi, &o4[1]);
}

extern "C" void kernel_launch(void* const* d_in, const int* in_sizes, int n_in,
                              void* d_out, int out_size, void* d_ws, size_t ws_size,
                              hipStream_t stream) {
    const float* x  = (const float*)d_in[0];
    const float* gW = (const float*)d_in[1];
    const float* gb = (const float*)d_in[2];
    const float* W1 = (const float*)d_in[3];
    const float* b1 = (const float*)d_in[4];
    const float* W2 = (const float*)d_in[5];
    const float* b2 = (const float*)d_in[6];
    float* out    = (float*)d_out;                 // [B, C]
    float* gw_out = out + (size_t)B_ * C_;         // [B, E]

    char* ws = (char*)d_ws;
    size_t off = 0;
    auto alloc = [&](size_t bytes) -> char* {
        char* p = ws + off;
        off = (off + bytes + 255) & ~(size_t)255;
        return p;
    };
    int*            counts  = (int*)alloc(E_ * 4);
    int*            rowlist = (int*)alloc((size_t)E_ * B_ * 4);
    float*          wtslist = (float*)alloc((size_t)E_ * B_ * 4);
    unsigned short* W2b     = (unsigned short*)alloc((size_t)E_ * C_ * H_ * 2);
    unsigned short* hbuf    = (unsigned short*)alloc((size_t)3 * B_ * H_ * 2);
    // union region: {xb (67MB) + W1b (50MB)} live until gemm1; sbuf16 (101MB)
    // live only during gemm2+combine.  sbuf16 fits inside the PROVEN
    // xb+W1b footprint (117MB), so use_sbuf is true whenever the base
    // allocation (which all passing rounds already used) fits.
    size_t region_off = off;
    unsigned short* xb      = (unsigned short*)alloc((size_t)B_ * D_ * 2);
    unsigned short* W1b     = (unsigned short*)alloc((size_t)E_ * H_ * D_ * 2);
    unsigned short* sbuf    = (unsigned short*)(ws + region_off);
    size_t sbuf_end = region_off + (size_t)3 * B_ * C_ * 2;
    bool use_sbuf = (ws_size == 0) || (sbuf_end <= ws_size);
    (void)in_sizes; (void)n_in; (void)out_size;

    hipMemsetAsync(counts, 0, E_ * 4, stream);
    if (!use_sbuf) hipMemsetAsync(out, 0, (size_t)B_ * C_ * 4, stream);

    gate_kernel<<<B_ / 4, 256, 0, stream>>>(x, gW, gb, gw_out, counts, rowlist, wtslist, xb);
    cast_f32_bf16<<<(E_ * H_ * D_ / 4) / 256, 256, 0, stream>>>(W1, W1b, E_ * H_ * D_ / 4);
    cast_f32_bf16<<<(E_ * C_ * H_ / 4) / 256, 256, 0, stream>>>(W2, W2b, E_ * C_ * H_ / 4);
    gemm1_kernel<<<dim3(8 * (B_ / 256), 1, E_), 512, 0, stream>>>(xb, W1b, b1, counts, rowlist, hbuf);
    gemm2_kernel<<<dim3(4 * (B_ / 256), 1, E_), 512, 0, stream>>>(hbuf, W2b, b2, counts, rowlist, wtslist,
                                                                  use_sbuf ? sbuf : (unsigned short*)nullptr, out);
    if (use_sbuf)
        combine_kernel<<<(B_ * C_ / 8) / 256, 256, 0, stream>>>(sbuf, out);
}